// Round 2
// baseline (249.934 us; speedup 1.0000x reference)
//
#include <hip/hip_runtime.h>
#include <math.h>

// NT=64, NR=4, DK=2, KU=8, BR=16, BATCH=256
// channel:    [B][64][4][16][16] f32 (last dim: 8 re, 8 im)
// prediction: [B][2560] = U[4][2][16][16] ++ W[2][2][16][8]
// out:        [B][64][2][8][2] f32
//
// R10 = R9 with the register cap fixed: __launch_bounds__(1024, 4).
// R9's __launch_bounds__(1024) let the compiler cap VGPR at 64 -> massive
// scratch spill (WRITE_SIZE 2MB -> 271MB, dur 95 -> 180us). Requesting
// 4 waves/SIMD explicitly sets the cap to 512/4 = 128, which covers the
// ~120-register natural pressure measured in R8. Structure unchanged:
//  - quad phase: 4 f-quarters x 256 threads, 4 fi iters each
//  - pair-tree merge of partials -> straight into GJ registers
//  - Gauss-Jordan: 16 threads/row x 5 cols

#define SAUG 84   // float2 stride of Aug rows
#define STP  65   // float4 stride of paired TtP/HtP rows

namespace {
union alignas(16) ShU {
    struct { float4 TtP[2][4][8][STP]; float4 HtP[2][4][8][STP]; } p1; // 133120 B
    struct { float2 A[64][SAUG]; float2 B[64][SAUG]; } aug;            // 86016 B
};
union alignas(16) ShV {
    struct { float2 U[4 * 258]; float W[512]; } in;                    // 10304 B
    float2 xout[64][17];                                               // 8704 B
};
}

__device__ __forceinline__ float2 cmul(float2 x, float2 y) {
    return make_float2(x.x * y.x - x.y * y.y, x.x * y.y + x.y * y.x);
}

__global__ __launch_bounds__(1024, 4)
void uw2v_kernel(const float* __restrict__ channel,
                 const float* __restrict__ prediction,
                 float2* __restrict__ out)
{
    __shared__ ShU sh;
    __shared__ ShV sv;
    __shared__ alignas(16) float2 prow[2][80];   // pivot-row double buffer
    __shared__ float2 redbuf[16];
    __shared__ float  fred[16];

    const int b   = blockIdx.x;
    const int tid = threadIdx.x;
    const int wv  = tid >> 6;
    const float* pred = prediction + (size_t)b * 2560;
    const float* chan = channel + (size_t)b * 65536;

    // ---- load U (re/im merged, padded per-r stride) and W ----
    {
        int m = tid;                                 // [r][d][f][k], 1024 entries
        int r = m >> 8, d = (m >> 7) & 1, f = (m >> 3) & 15, k = m & 7;
        const float* src = pred + (((r * 2 + d) * 16 + f) << 4);
        sv.in.U[r * 258 + ((d * 16 + f) << 3) + k] = make_float2(src[k], src[k + 8]);
    }
    if (tid < 512) sv.in.W[tid] = pred[2048 + tid];
    __syncthreads();

    const int grp = tid >> 8;                        // f-quarter 0..3
    const int lt  = tid & 255;
    const int t4 = lt >> 2, r4 = lt & 3;
    const int a  = lt >> 4, bb = lt & 15;
    const int bit0 = r4 & 1, bit1 = (r4 >> 1) & 1;
    const int kkb  = 4 * bit0 + 2 * bit1;            // owned k-slice base (even)
    const int mpb  = kkb >> 1;                       // owned m-pair row (0..3)
    const int fbase = grp << 2;
    const int tr_r = lt >> 5, tr_d = (lt >> 4) & 1, tr_e = (lt >> 3) & 1, tr_k = lt & 7;

    // split accumulators: accA = sum t_re*h, accB = sum t_im*h (h = (re,im))
    float2 accA[4][4], accB[4][4];
    #pragma unroll
    for (int i = 0; i < 4; ++i)
        #pragma unroll
        for (int j = 0; j < 4; ++j) {
            accA[i][j] = make_float2(0.f, 0.f);
            accB[i][j] = make_float2(0.f, 0.f);
        }
    float2 huw[4] = {make_float2(0,0), make_float2(0,0), make_float2(0,0), make_float2(0,0)};
    float2 tracc  = make_float2(0.f, 0.f);

    const float* hbase = chan + ((t4 * 4 + r4) << 8) + (fbase << 4);

    #pragma unroll 1
    for (int fi = 0; fi < 4; ++fi) {
        const int f = fbase + fi;
        const float4 ca = *(const float4*)(hbase + (fi << 4) + 0);
        const float4 cb = *(const float4*)(hbase + (fi << 4) + 4);
        const float4 ci = *(const float4*)(hbase + (fi << 4) + 8);
        const float4 cd = *(const float4*)(hbase + (fi << 4) + 12);

        const float4* U0p = (const float4*)&sv.in.U[r4 * 258 + (f << 3)];        // d=0
        const float4* U1p = (const float4*)&sv.in.U[r4 * 258 + ((16 + f) << 3)]; // d=1
        const float4 u0q0 = U0p[0], u0q1 = U0p[1], u0q2 = U0p[2], u0q3 = U0p[3];
        const float4 u1q0 = U1p[0], u1q1 = U1p[1], u1q2 = U1p[2], u1q3 = U1p[3];

        // partials: val0[k] = conj(H)*U (d=0, m=k), val1[k] (d=1, m=8+k)
        float2 val0[8], val1[8];
        #define MK2(K, HR, HI, U0R, U0I, U1R, U1I) \
            val0[K] = make_float2((HR)*(U0R) + (HI)*(U0I), (HR)*(U0I) - (HI)*(U0R)); \
            val1[K] = make_float2((HR)*(U1R) + (HI)*(U1I), (HR)*(U1I) - (HI)*(U1R));
        MK2(0, ca.x, ci.x, u0q0.x, u0q0.y, u1q0.x, u1q0.y)
        MK2(1, ca.y, ci.y, u0q0.z, u0q0.w, u1q0.z, u1q0.w)
        MK2(2, ca.z, ci.z, u0q1.x, u0q1.y, u1q1.x, u1q1.y)
        MK2(3, ca.w, ci.w, u0q1.z, u0q1.w, u1q1.z, u1q1.w)
        MK2(4, cb.x, cd.x, u0q2.x, u0q2.y, u1q2.x, u1q2.y)
        MK2(5, cb.y, cd.y, u0q2.z, u0q2.w, u1q2.z, u1q2.w)
        MK2(6, cb.z, cd.z, u0q3.x, u0q3.y, u1q3.x, u1q3.y)
        MK2(7, cb.w, cd.w, u0q3.z, u0q3.w, u1q3.z, u1q3.w)
        #undef MK2

        // stage 1 (xor 1): keep k in {4*bit0 .. 4*bit0+3}
        float2 s1d0[4], s1d1[4];
        #pragma unroll
        for (int q = 0; q < 4; ++q) {
            float2 k0 = bit0 ? val0[4 + q] : val0[q];
            float2 n0 = bit0 ? val0[q]     : val0[4 + q];
            float2 k1 = bit0 ? val1[4 + q] : val1[q];
            float2 n1 = bit0 ? val1[q]     : val1[4 + q];
            n0.x = __shfl_xor(n0.x, 1); n0.y = __shfl_xor(n0.y, 1);
            n1.x = __shfl_xor(n1.x, 1); n1.y = __shfl_xor(n1.y, 1);
            s1d0[q] = make_float2(k0.x + n0.x, k0.y + n0.y);
            s1d1[q] = make_float2(k1.x + n1.x, k1.y + n1.y);
        }
        // stage 2 (xor 2): keep q in {2*bit1, 2*bit1+1} -> hh[kkb+jj]
        float2 h0[2], h1[2];
        #pragma unroll
        for (int jj = 0; jj < 2; ++jj) {
            float2 k0 = bit1 ? s1d0[2 + jj] : s1d0[jj];
            float2 n0 = bit1 ? s1d0[jj]     : s1d0[2 + jj];
            float2 k1 = bit1 ? s1d1[2 + jj] : s1d1[jj];
            float2 n1 = bit1 ? s1d1[jj]     : s1d1[2 + jj];
            n0.x = __shfl_xor(n0.x, 2); n0.y = __shfl_xor(n0.y, 2);
            n1.x = __shfl_xor(n1.x, 2); n1.y = __shfl_xor(n1.y, 2);
            h0[jj] = make_float2(k0.x + n0.x, k0.y + n0.y);
            h1[jj] = make_float2(k1.x + n1.x, k1.y + n1.y);
        }

        // tr_UWU partial (128 lanes per group; wave-uniform branch)
        if (lt < 128) {
            float w   = sv.in.W[((tr_d * 2 + tr_e) * 16 + f) * 8 + tr_k];
            float2 u1 = sv.in.U[tr_r * 258 + ((tr_d * 16 + f) << 3) + tr_k];
            float2 u2 = sv.in.U[tr_r * 258 + ((tr_e * 16 + f) << 3) + tr_k];
            tracc.x += w * (u1.x * u2.x + u1.y * u2.y);
            tracc.y += w * (u1.y * u2.x - u1.x * u2.y);
        }

        // T pairs + H pairs (b128 writes, m-pair rows)
        const int p = fi & 1;
        #pragma unroll
        for (int e = 0; e < 2; ++e) {
            float w0a = sv.in.W[(e * 16 + f) * 8 + kkb];
            float w0b = sv.in.W[(e * 16 + f) * 8 + kkb + 1];
            float w1a = sv.in.W[((2 + e) * 16 + f) * 8 + kkb];
            float w1b = sv.in.W[((2 + e) * 16 + f) * 8 + kkb + 1];
            float2 tva = make_float2(h0[0].x * w0a + h1[0].x * w1a,
                                     h0[0].y * w0a + h1[0].y * w1a);
            float2 tvb = make_float2(h0[1].x * w0b + h1[1].x * w1b,
                                     h0[1].y * w0b + h1[1].y * w1b);
            sh.p1.TtP[p][grp][e * 4 + mpb][t4] = make_float4(tva.x, tva.y, tvb.x, tvb.y);
            huw[e * 2 + 0].x += tva.x; huw[e * 2 + 0].y += tva.y;
            huw[e * 2 + 1].x += tvb.x; huw[e * 2 + 1].y += tvb.y;
        }
        sh.p1.HtP[p][grp][mpb][t4]     = make_float4(h0[0].x, h0[0].y, h0[1].x, h0[1].y);
        sh.p1.HtP[p][grp][4 + mpb][t4] = make_float4(h1[0].x, h1[0].y, h1[1].x, h1[1].y);
        __syncthreads();

        // quad: accA/accB [i][j] over m-pairs (b128 reads, broadcast-friendly)
        #pragma unroll
        for (int mp = 0; mp < 8; ++mp) {
            float4 tq[4], hq[4];
            #pragma unroll
            for (int i = 0; i < 4; ++i) tq[i] = sh.p1.TtP[p][grp][mp][a + 16 * i];
            #pragma unroll
            for (int j = 0; j < 4; ++j) hq[j] = sh.p1.HtP[p][grp][mp][bb + 16 * j];
            #pragma unroll
            for (int i = 0; i < 4; ++i)
                #pragma unroll
                for (int j = 0; j < 4; ++j) {
                    float2 va = accA[i][j], vb = accB[i][j];
                    va.x = fmaf(tq[i].x, hq[j].x, va.x);
                    va.y = fmaf(tq[i].x, hq[j].y, va.y);
                    vb.x = fmaf(tq[i].y, hq[j].x, vb.x);
                    vb.y = fmaf(tq[i].y, hq[j].y, vb.y);
                    va.x = fmaf(tq[i].z, hq[j].z, va.x);
                    va.y = fmaf(tq[i].z, hq[j].w, va.y);
                    vb.x = fmaf(tq[i].w, hq[j].z, vb.x);
                    vb.y = fmaf(tq[i].w, hq[j].w, vb.y);
                    accA[i][j] = va; accB[i][j] = vb;
                }
        }
    }

    // ---- tr_UWU block reduction (barrier also retires last TtP reads) ----
    #pragma unroll
    for (int off = 32; off; off >>= 1) {
        tracc.x += __shfl_xor(tracc.x, off);
        tracc.y += __shfl_xor(tracc.y, off);
    }
    if ((tid & 63) == 0) redbuf[wv] = tracc;
    __syncthreads();
    float2 trv = make_float2(0.f, 0.f);
    #pragma unroll
    for (int w = 0; w < 16; ++w) { trv.x += redbuf[w].x; trv.y += redbuf[w].y; }
    trv.x *= 0.1f; trv.y *= 0.1f;

    // ---- pair-tree merge of the 4 f-quarter partials ----
    // qacc = (accA.x + accB.y, accB.x - accA.y)
    if ((grp & 1) == 0) {                            // g0 -> AugA, g2 -> AugB
        float2 (*Dst)[SAUG] = (grp == 0) ? sh.aug.A : sh.aug.B;
        #pragma unroll
        for (int i = 0; i < 4; ++i)
            #pragma unroll
            for (int j = 0; j < 4; ++j) {
                Dst[a + 16 * i][bb + 16 * j] =
                    make_float2(accA[i][j].x + accB[i][j].y,
                                accB[i][j].x - accA[i][j].y);
            }
        #pragma unroll
        for (int e = 0; e < 2; ++e)
            #pragma unroll
            for (int jj = 0; jj < 2; ++jj)
                Dst[t4][64 + e * 8 + kkb + jj] = huw[e * 2 + jj];
    }
    __syncthreads();
    if (grp & 1) {                                   // g1 RMW AugA, g3 RMW AugB
        float2 (*Dst)[SAUG] = (grp == 1) ? sh.aug.A : sh.aug.B;
        #pragma unroll
        for (int i = 0; i < 4; ++i)
            #pragma unroll
            for (int j = 0; j < 4; ++j) {
                float2 v = Dst[a + 16 * i][bb + 16 * j];
                v.x += accA[i][j].x + accB[i][j].y;
                v.y += accB[i][j].x - accA[i][j].y;
                Dst[a + 16 * i][bb + 16 * j] = v;
            }
        #pragma unroll
        for (int e = 0; e < 2; ++e)
            #pragma unroll
            for (int jj = 0; jj < 2; ++jj) {
                int col = 64 + e * 8 + kkb + jj;
                float2 v = Dst[t4][col];
                v.x += huw[e * 2 + jj].x; v.y += huw[e * 2 + jj].y;
                Dst[t4][col] = v;
            }
    }
    __syncthreads();

    // ---- combine A+B (+trv on diag) straight into GJ registers ----
    const int gi = tid >> 4, gc = tid & 15;          // 64 rows x 16 col-slices
    const int cb = gc * 5;                           // 5 cols per thread
    const int lanebase = (tid & 63) & 48;

    float2 xr[5];
    #pragma unroll
    for (int c = 0; c < 5; ++c) {
        float2 v = sh.aug.A[gi][cb + c];
        float2 w = sh.aug.B[gi][cb + c];
        v.x += w.x; v.y += w.y;
        if (gi == cb + c) { v.x += trv.x; v.y += trv.y; }
        xr[c] = v;
    }
    if (gi == 0) {
        #pragma unroll
        for (int c = 0; c < 5; ++c) prow[0][cb + c] = xr[c];
    }
    __syncthreads();

    // ---- Gauss-Jordan: register-resident rows, diagonal pivots ----
    float2 myipv = make_float2(0.f, 0.f);

    #pragma unroll 1
    for (int ks = 0; ks < 64; ++ks) {
        const int pb = ks & 1;
        float2 pr[5];
        #pragma unroll
        for (int c = 0; c < 5; ++c) pr[c] = prow[pb][cb + c];

        float2 z = prow[pb][ks];
        float  zi = 1.0f / (z.x * z.x + z.y * z.y);
        float2 ipv = make_float2(z.x * zi, -z.y * zi);

        float2 cand = make_float2(0.f, 0.f);
        #pragma unroll
        for (int c = 0; c < 5; ++c)
            if (cb + c == ks) cand = xr[c];
        int srcl = lanebase + (ks / 5);
        float2 Lv;
        Lv.x = __shfl(cand.x, srcl);
        Lv.y = __shfl(cand.y, srcl);

        if (gi == ks) {
            myipv = ipv;
        } else {
            float2 L = cmul(Lv, ipv);
            #pragma unroll
            for (int c = 0; c < 5; ++c) {
                xr[c].x -= L.x * pr[c].x - L.y * pr[c].y;
                xr[c].y -= L.x * pr[c].y + L.y * pr[c].x;
            }
        }
        if (gi == ks + 1) {
            #pragma unroll
            for (int c = 0; c < 5; ++c) prow[pb ^ 1][cb + c] = xr[c];
        }
        __syncthreads();
    }

    // ---- extract solution (cols 64..79), normalize, write ----
    float ss = 0.f;
    if (gc >= 12) {
        #pragma unroll
        for (int c = 0; c < 5; ++c) {
            int col = cb + c;
            if (col >= 64) {
                float2 xv = cmul(xr[c], myipv);
                ss += xv.x * xv.x + xv.y * xv.y;
                sv.xout[gi][col - 64] = xv;
            }
        }
    }
    #pragma unroll
    for (int off = 32; off; off >>= 1) ss += __shfl_xor(ss, off);
    if ((tid & 63) == 0) fred[wv] = ss;
    __syncthreads();
    float total = 0.f;
    #pragma unroll
    for (int w = 0; w < 16; ++w) total += fred[w];
    float invn = rsqrtf(total);
    {
        float2 v = sv.xout[tid >> 4][tid & 15];
        out[(size_t)b * 1024 + tid] = make_float2(v.x * invn, v.y * invn);
    }
}

extern "C" void kernel_launch(void* const* d_in, const int* in_sizes, int n_in,
                              void* d_out, int out_size, void* d_ws, size_t ws_size,
                              hipStream_t stream) {
    const float* channel    = (const float*)d_in[0];
    const float* prediction = (const float*)d_in[1];
    int batch = in_sizes[0] / 65536;   // 256
    uw2v_kernel<<<dim3(batch), dim3(1024), 0, stream>>>(channel, prediction,
                                                        (float2*)d_out);
}

// Round 3
// 249.567 us; speedup vs baseline: 1.0015x; 1.0015x over previous
//
#include <hip/hip_runtime.h>
#include <math.h>

// NT=64, NR=4, DK=2, KU=8, BR=16, BATCH=256
// channel:    [B][64][4][16][16] f32 (last dim: 8 re, 8 im)
// prediction: [B][2560] = U[4][2][16][16] ++ W[2][2][16][8]
// out:        [B][64][2][8][2] f32
//
// R11 = R9 body + amdgpu_waves_per_eu(4,4).
// R9/R10 compiled to VGPR=64 + 272MB scratch: with a 1024-thread block the
// allocator targets 8 waves/EU (it ignores the 141KB-LDS occupancy limit)
// and budgets 64 VGPRs. __launch_bounds__' 2nd arg only sets the MIN
// waves/EU (already 4 implicitly) -> no-op. Pinning min=max=4 via
// amdgpu_waves_per_eu(4,4) raises the budget to 512/4=128 VGPRs, covering
// the ~120-reg natural pressure measured in R8. LDS already limits us to
// 1 block/CU, so nothing is lost. Structure unchanged:
//  - quad phase: 4 f-quarters x 256 threads, 4 fi iters each
//  - pair-tree merge of partials -> straight into GJ registers
//  - Gauss-Jordan: 16 threads/row x 5 cols

#define SAUG 84   // float2 stride of Aug rows
#define STP  65   // float4 stride of paired TtP/HtP rows

namespace {
union alignas(16) ShU {
    struct { float4 TtP[2][4][8][STP]; float4 HtP[2][4][8][STP]; } p1; // 133120 B
    struct { float2 A[64][SAUG]; float2 B[64][SAUG]; } aug;            // 86016 B
};
union alignas(16) ShV {
    struct { float2 U[4 * 258]; float W[512]; } in;                    // 10304 B
    float2 xout[64][17];                                               // 8704 B
};
}

__device__ __forceinline__ float2 cmul(float2 x, float2 y) {
    return make_float2(x.x * y.x - x.y * y.y, x.x * y.y + x.y * y.x);
}

__global__ __launch_bounds__(1024)
__attribute__((amdgpu_waves_per_eu(4, 4)))
void uw2v_kernel(const float* __restrict__ channel,
                 const float* __restrict__ prediction,
                 float2* __restrict__ out)
{
    __shared__ ShU sh;
    __shared__ ShV sv;
    __shared__ alignas(16) float2 prow[2][80];   // pivot-row double buffer
    __shared__ float2 redbuf[16];
    __shared__ float  fred[16];

    const int b   = blockIdx.x;
    const int tid = threadIdx.x;
    const int wv  = tid >> 6;
    const float* pred = prediction + (size_t)b * 2560;
    const float* chan = channel + (size_t)b * 65536;

    // ---- load U (re/im merged, padded per-r stride) and W ----
    {
        int m = tid;                                 // [r][d][f][k], 1024 entries
        int r = m >> 8, d = (m >> 7) & 1, f = (m >> 3) & 15, k = m & 7;
        const float* src = pred + (((r * 2 + d) * 16 + f) << 4);
        sv.in.U[r * 258 + ((d * 16 + f) << 3) + k] = make_float2(src[k], src[k + 8]);
    }
    if (tid < 512) sv.in.W[tid] = pred[2048 + tid];
    __syncthreads();

    const int grp = tid >> 8;                        // f-quarter 0..3
    const int lt  = tid & 255;
    const int t4 = lt >> 2, r4 = lt & 3;
    const int a  = lt >> 4, bb = lt & 15;
    const int bit0 = r4 & 1, bit1 = (r4 >> 1) & 1;
    const int kkb  = 4 * bit0 + 2 * bit1;            // owned k-slice base (even)
    const int mpb  = kkb >> 1;                       // owned m-pair row (0..3)
    const int fbase = grp << 2;
    const int tr_r = lt >> 5, tr_d = (lt >> 4) & 1, tr_e = (lt >> 3) & 1, tr_k = lt & 7;

    // split accumulators: accA = sum t_re*h, accB = sum t_im*h (h = (re,im))
    float2 accA[4][4], accB[4][4];
    #pragma unroll
    for (int i = 0; i < 4; ++i)
        #pragma unroll
        for (int j = 0; j < 4; ++j) {
            accA[i][j] = make_float2(0.f, 0.f);
            accB[i][j] = make_float2(0.f, 0.f);
        }
    float2 huw[4] = {make_float2(0,0), make_float2(0,0), make_float2(0,0), make_float2(0,0)};
    float2 tracc  = make_float2(0.f, 0.f);

    const float* hbase = chan + ((t4 * 4 + r4) << 8) + (fbase << 4);

    #pragma unroll 1
    for (int fi = 0; fi < 4; ++fi) {
        const int f = fbase + fi;
        const float4 ca = *(const float4*)(hbase + (fi << 4) + 0);
        const float4 cb = *(const float4*)(hbase + (fi << 4) + 4);
        const float4 ci = *(const float4*)(hbase + (fi << 4) + 8);
        const float4 cd = *(const float4*)(hbase + (fi << 4) + 12);

        const float4* U0p = (const float4*)&sv.in.U[r4 * 258 + (f << 3)];        // d=0
        const float4* U1p = (const float4*)&sv.in.U[r4 * 258 + ((16 + f) << 3)]; // d=1
        const float4 u0q0 = U0p[0], u0q1 = U0p[1], u0q2 = U0p[2], u0q3 = U0p[3];
        const float4 u1q0 = U1p[0], u1q1 = U1p[1], u1q2 = U1p[2], u1q3 = U1p[3];

        // partials: val0[k] = conj(H)*U (d=0, m=k), val1[k] (d=1, m=8+k)
        float2 val0[8], val1[8];
        #define MK2(K, HR, HI, U0R, U0I, U1R, U1I) \
            val0[K] = make_float2((HR)*(U0R) + (HI)*(U0I), (HR)*(U0I) - (HI)*(U0R)); \
            val1[K] = make_float2((HR)*(U1R) + (HI)*(U1I), (HR)*(U1I) - (HI)*(U1R));
        MK2(0, ca.x, ci.x, u0q0.x, u0q0.y, u1q0.x, u1q0.y)
        MK2(1, ca.y, ci.y, u0q0.z, u0q0.w, u1q0.z, u1q0.w)
        MK2(2, ca.z, ci.z, u0q1.x, u0q1.y, u1q1.x, u1q1.y)
        MK2(3, ca.w, ci.w, u0q1.z, u0q1.w, u1q1.z, u1q1.w)
        MK2(4, cb.x, cd.x, u0q2.x, u0q2.y, u1q2.x, u1q2.y)
        MK2(5, cb.y, cd.y, u0q2.z, u0q2.w, u1q2.z, u1q2.w)
        MK2(6, cb.z, cd.z, u0q3.x, u0q3.y, u1q3.x, u1q3.y)
        MK2(7, cb.w, cd.w, u0q3.z, u0q3.w, u1q3.z, u1q3.w)
        #undef MK2

        // stage 1 (xor 1): keep k in {4*bit0 .. 4*bit0+3}
        float2 s1d0[4], s1d1[4];
        #pragma unroll
        for (int q = 0; q < 4; ++q) {
            float2 k0 = bit0 ? val0[4 + q] : val0[q];
            float2 n0 = bit0 ? val0[q]     : val0[4 + q];
            float2 k1 = bit0 ? val1[4 + q] : val1[q];
            float2 n1 = bit0 ? val1[q]     : val1[4 + q];
            n0.x = __shfl_xor(n0.x, 1); n0.y = __shfl_xor(n0.y, 1);
            n1.x = __shfl_xor(n1.x, 1); n1.y = __shfl_xor(n1.y, 1);
            s1d0[q] = make_float2(k0.x + n0.x, k0.y + n0.y);
            s1d1[q] = make_float2(k1.x + n1.x, k1.y + n1.y);
        }
        // stage 2 (xor 2): keep q in {2*bit1, 2*bit1+1} -> hh[kkb+jj]
        float2 h0[2], h1[2];
        #pragma unroll
        for (int jj = 0; jj < 2; ++jj) {
            float2 k0 = bit1 ? s1d0[2 + jj] : s1d0[jj];
            float2 n0 = bit1 ? s1d0[jj]     : s1d0[2 + jj];
            float2 k1 = bit1 ? s1d1[2 + jj] : s1d1[jj];
            float2 n1 = bit1 ? s1d1[jj]     : s1d1[2 + jj];
            n0.x = __shfl_xor(n0.x, 2); n0.y = __shfl_xor(n0.y, 2);
            n1.x = __shfl_xor(n1.x, 2); n1.y = __shfl_xor(n1.y, 2);
            h0[jj] = make_float2(k0.x + n0.x, k0.y + n0.y);
            h1[jj] = make_float2(k1.x + n1.x, k1.y + n1.y);
        }

        // tr_UWU partial (128 lanes per group; wave-uniform branch)
        if (lt < 128) {
            float w   = sv.in.W[((tr_d * 2 + tr_e) * 16 + f) * 8 + tr_k];
            float2 u1 = sv.in.U[tr_r * 258 + ((tr_d * 16 + f) << 3) + tr_k];
            float2 u2 = sv.in.U[tr_r * 258 + ((tr_e * 16 + f) << 3) + tr_k];
            tracc.x += w * (u1.x * u2.x + u1.y * u2.y);
            tracc.y += w * (u1.y * u2.x - u1.x * u2.y);
        }

        // T pairs + H pairs (b128 writes, m-pair rows)
        const int p = fi & 1;
        #pragma unroll
        for (int e = 0; e < 2; ++e) {
            float w0a = sv.in.W[(e * 16 + f) * 8 + kkb];
            float w0b = sv.in.W[(e * 16 + f) * 8 + kkb + 1];
            float w1a = sv.in.W[((2 + e) * 16 + f) * 8 + kkb];
            float w1b = sv.in.W[((2 + e) * 16 + f) * 8 + kkb + 1];
            float2 tva = make_float2(h0[0].x * w0a + h1[0].x * w1a,
                                     h0[0].y * w0a + h1[0].y * w1a);
            float2 tvb = make_float2(h0[1].x * w0b + h1[1].x * w1b,
                                     h0[1].y * w0b + h1[1].y * w1b);
            sh.p1.TtP[p][grp][e * 4 + mpb][t4] = make_float4(tva.x, tva.y, tvb.x, tvb.y);
            huw[e * 2 + 0].x += tva.x; huw[e * 2 + 0].y += tva.y;
            huw[e * 2 + 1].x += tvb.x; huw[e * 2 + 1].y += tvb.y;
        }
        sh.p1.HtP[p][grp][mpb][t4]     = make_float4(h0[0].x, h0[0].y, h0[1].x, h0[1].y);
        sh.p1.HtP[p][grp][4 + mpb][t4] = make_float4(h1[0].x, h1[0].y, h1[1].x, h1[1].y);
        __syncthreads();

        // quad: accA/accB [i][j] over m-pairs (b128 reads, broadcast-friendly)
        #pragma unroll
        for (int mp = 0; mp < 8; ++mp) {
            float4 tq[4], hq[4];
            #pragma unroll
            for (int i = 0; i < 4; ++i) tq[i] = sh.p1.TtP[p][grp][mp][a + 16 * i];
            #pragma unroll
            for (int j = 0; j < 4; ++j) hq[j] = sh.p1.HtP[p][grp][mp][bb + 16 * j];
            #pragma unroll
            for (int i = 0; i < 4; ++i)
                #pragma unroll
                for (int j = 0; j < 4; ++j) {
                    float2 va = accA[i][j], vb = accB[i][j];
                    va.x = fmaf(tq[i].x, hq[j].x, va.x);
                    va.y = fmaf(tq[i].x, hq[j].y, va.y);
                    vb.x = fmaf(tq[i].y, hq[j].x, vb.x);
                    vb.y = fmaf(tq[i].y, hq[j].y, vb.y);
                    va.x = fmaf(tq[i].z, hq[j].z, va.x);
                    va.y = fmaf(tq[i].z, hq[j].w, va.y);
                    vb.x = fmaf(tq[i].w, hq[j].z, vb.x);
                    vb.y = fmaf(tq[i].w, hq[j].w, vb.y);
                    accA[i][j] = va; accB[i][j] = vb;
                }
        }
    }

    // ---- tr_UWU block reduction (barrier also retires last TtP reads) ----
    #pragma unroll
    for (int off = 32; off; off >>= 1) {
        tracc.x += __shfl_xor(tracc.x, off);
        tracc.y += __shfl_xor(tracc.y, off);
    }
    if ((tid & 63) == 0) redbuf[wv] = tracc;
    __syncthreads();
    float2 trv = make_float2(0.f, 0.f);
    #pragma unroll
    for (int w = 0; w < 16; ++w) { trv.x += redbuf[w].x; trv.y += redbuf[w].y; }
    trv.x *= 0.1f; trv.y *= 0.1f;

    // ---- pair-tree merge of the 4 f-quarter partials ----
    // qacc = (accA.x + accB.y, accB.x - accA.y)
    if ((grp & 1) == 0) {                            // g0 -> AugA, g2 -> AugB
        float2 (*Dst)[SAUG] = (grp == 0) ? sh.aug.A : sh.aug.B;
        #pragma unroll
        for (int i = 0; i < 4; ++i)
            #pragma unroll
            for (int j = 0; j < 4; ++j) {
                Dst[a + 16 * i][bb + 16 * j] =
                    make_float2(accA[i][j].x + accB[i][j].y,
                                accB[i][j].x - accA[i][j].y);
            }
        #pragma unroll
        for (int e = 0; e < 2; ++e)
            #pragma unroll
            for (int jj = 0; jj < 2; ++jj)
                Dst[t4][64 + e * 8 + kkb + jj] = huw[e * 2 + jj];
    }
    __syncthreads();
    if (grp & 1) {                                   // g1 RMW AugA, g3 RMW AugB
        float2 (*Dst)[SAUG] = (grp == 1) ? sh.aug.A : sh.aug.B;
        #pragma unroll
        for (int i = 0; i < 4; ++i)
            #pragma unroll
            for (int j = 0; j < 4; ++j) {
                float2 v = Dst[a + 16 * i][bb + 16 * j];
                v.x += accA[i][j].x + accB[i][j].y;
                v.y += accB[i][j].x - accA[i][j].y;
                Dst[a + 16 * i][bb + 16 * j] = v;
            }
        #pragma unroll
        for (int e = 0; e < 2; ++e)
            #pragma unroll
            for (int jj = 0; jj < 2; ++jj) {
                int col = 64 + e * 8 + kkb + jj;
                float2 v = Dst[t4][col];
                v.x += huw[e * 2 + jj].x; v.y += huw[e * 2 + jj].y;
                Dst[t4][col] = v;
            }
    }
    __syncthreads();

    // ---- combine A+B (+trv on diag) straight into GJ registers ----
    const int gi = tid >> 4, gc = tid & 15;          // 64 rows x 16 col-slices
    const int cb = gc * 5;                           // 5 cols per thread
    const int lanebase = (tid & 63) & 48;

    float2 xr[5];
    #pragma unroll
    for (int c = 0; c < 5; ++c) {
        float2 v = sh.aug.A[gi][cb + c];
        float2 w = sh.aug.B[gi][cb + c];
        v.x += w.x; v.y += w.y;
        if (gi == cb + c) { v.x += trv.x; v.y += trv.y; }
        xr[c] = v;
    }
    if (gi == 0) {
        #pragma unroll
        for (int c = 0; c < 5; ++c) prow[0][cb + c] = xr[c];
    }
    __syncthreads();

    // ---- Gauss-Jordan: register-resident rows, diagonal pivots ----
    float2 myipv = make_float2(0.f, 0.f);

    #pragma unroll 1
    for (int ks = 0; ks < 64; ++ks) {
        const int pb = ks & 1;
        float2 pr[5];
        #pragma unroll
        for (int c = 0; c < 5; ++c) pr[c] = prow[pb][cb + c];

        float2 z = prow[pb][ks];
        float  zi = 1.0f / (z.x * z.x + z.y * z.y);
        float2 ipv = make_float2(z.x * zi, -z.y * zi);

        float2 cand = make_float2(0.f, 0.f);
        #pragma unroll
        for (int c = 0; c < 5; ++c)
            if (cb + c == ks) cand = xr[c];
        int srcl = lanebase + (ks / 5);
        float2 Lv;
        Lv.x = __shfl(cand.x, srcl);
        Lv.y = __shfl(cand.y, srcl);

        if (gi == ks) {
            myipv = ipv;
        } else {
            float2 L = cmul(Lv, ipv);
            #pragma unroll
            for (int c = 0; c < 5; ++c) {
                xr[c].x -= L.x * pr[c].x - L.y * pr[c].y;
                xr[c].y -= L.x * pr[c].y + L.y * pr[c].x;
            }
        }
        if (gi == ks + 1) {
            #pragma unroll
            for (int c = 0; c < 5; ++c) prow[pb ^ 1][cb + c] = xr[c];
        }
        __syncthreads();
    }

    // ---- extract solution (cols 64..79), normalize, write ----
    float ss = 0.f;
    if (gc >= 12) {
        #pragma unroll
        for (int c = 0; c < 5; ++c) {
            int col = cb + c;
            if (col >= 64) {
                float2 xv = cmul(xr[c], myipv);
                ss += xv.x * xv.x + xv.y * xv.y;
                sv.xout[gi][col - 64] = xv;
            }
        }
    }
    #pragma unroll
    for (int off = 32; off; off >>= 1) ss += __shfl_xor(ss, off);
    if ((tid & 63) == 0) fred[wv] = ss;
    __syncthreads();
    float total = 0.f;
    #pragma unroll
    for (int w = 0; w < 16; ++w) total += fred[w];
    float invn = rsqrtf(total);
    {
        float2 v = sv.xout[tid >> 4][tid & 15];
        out[(size_t)b * 1024 + tid] = make_float2(v.x * invn, v.y * invn);
    }
}

extern "C" void kernel_launch(void* const* d_in, const int* in_sizes, int n_in,
                              void* d_out, int out_size, void* d_ws, size_t ws_size,
                              hipStream_t stream) {
    const float* channel    = (const float*)d_in[0];
    const float* prediction = (const float*)d_in[1];
    int batch = in_sizes[0] / 65536;   // 256
    uw2v_kernel<<<dim3(batch), dim3(1024), 0, stream>>>(channel, prediction,
                                                        (float2*)d_out);
}

// Round 4
// 249.460 us; speedup vs baseline: 1.0019x; 1.0004x over previous
//
#include <hip/hip_runtime.h>
#include <math.h>

// NT=64, NR=4, DK=2, KU=8, BR=16, BATCH=256
// channel:    [B][64][4][16][16] f32 (last dim: 8 re, 8 im)
// prediction: [B][2560] = U[4][2][16][16] ++ W[2][2][16][8]
// out:        [B][64][2][8][2] f32
//
// R12 = R9 body; compile attributes changed to force VGPR budget = 128.
// History: R9 (__launch_bounds__(1024)) and R10 (…,4) and R11
// (amdgpu_waves_per_eu(4,4) alongside launch_bounds) ALL compiled to
// VGPR=64 + 272MB scratch spill -> 174us. The waves-per-EU knob is not
// reaching the allocator. This round: drop __launch_bounds__ entirely,
// use raw attributes amdgpu_flat_work_group_size(1024,1024) +
// amdgpu_waves_per_eu(4,4) + amdgpu_num_vgpr(128). amdgpu_num_vgpr
// overrides the occupancy-derived VGPR cap directly in getMaxNumVGPRs.
// LDS (141KB) caps residency at 1 WG = 16 waves = 4 waves/SIMD anyway,
// so a 128-VGPR budget costs nothing.
// Structure unchanged:
//  - quad phase: 4 f-quarters x 256 threads, 4 fi iters each
//  - pair-tree merge of partials -> straight into GJ registers
//  - Gauss-Jordan: 16 threads/row x 5 cols

#define SAUG 84   // float2 stride of Aug rows
#define STP  65   // float4 stride of paired TtP/HtP rows

namespace {
union alignas(16) ShU {
    struct { float4 TtP[2][4][8][STP]; float4 HtP[2][4][8][STP]; } p1; // 133120 B
    struct { float2 A[64][SAUG]; float2 B[64][SAUG]; } aug;            // 86016 B
};
union alignas(16) ShV {
    struct { float2 U[4 * 258]; float W[512]; } in;                    // 10304 B
    float2 xout[64][17];                                               // 8704 B
};
}

__device__ __forceinline__ float2 cmul(float2 x, float2 y) {
    return make_float2(x.x * y.x - x.y * y.y, x.x * y.y + x.y * y.x);
}

__global__
__attribute__((amdgpu_flat_work_group_size(1024, 1024)))
__attribute__((amdgpu_waves_per_eu(4, 4)))
__attribute__((amdgpu_num_vgpr(128)))
void uw2v_kernel(const float* __restrict__ channel,
                 const float* __restrict__ prediction,
                 float2* __restrict__ out)
{
    __shared__ ShU sh;
    __shared__ ShV sv;
    __shared__ alignas(16) float2 prow[2][80];   // pivot-row double buffer
    __shared__ float2 redbuf[16];
    __shared__ float  fred[16];

    const int b   = blockIdx.x;
    const int tid = threadIdx.x;
    const int wv  = tid >> 6;
    const float* pred = prediction + (size_t)b * 2560;
    const float* chan = channel + (size_t)b * 65536;

    // ---- load U (re/im merged, padded per-r stride) and W ----
    {
        int m = tid;                                 // [r][d][f][k], 1024 entries
        int r = m >> 8, d = (m >> 7) & 1, f = (m >> 3) & 15, k = m & 7;
        const float* src = pred + (((r * 2 + d) * 16 + f) << 4);
        sv.in.U[r * 258 + ((d * 16 + f) << 3) + k] = make_float2(src[k], src[k + 8]);
    }
    if (tid < 512) sv.in.W[tid] = pred[2048 + tid];
    __syncthreads();

    const int grp = tid >> 8;                        // f-quarter 0..3
    const int lt  = tid & 255;
    const int t4 = lt >> 2, r4 = lt & 3;
    const int a  = lt >> 4, bb = lt & 15;
    const int bit0 = r4 & 1, bit1 = (r4 >> 1) & 1;
    const int kkb  = 4 * bit0 + 2 * bit1;            // owned k-slice base (even)
    const int mpb  = kkb >> 1;                       // owned m-pair row (0..3)
    const int fbase = grp << 2;
    const int tr_r = lt >> 5, tr_d = (lt >> 4) & 1, tr_e = (lt >> 3) & 1, tr_k = lt & 7;

    // split accumulators: accA = sum t_re*h, accB = sum t_im*h (h = (re,im))
    float2 accA[4][4], accB[4][4];
    #pragma unroll
    for (int i = 0; i < 4; ++i)
        #pragma unroll
        for (int j = 0; j < 4; ++j) {
            accA[i][j] = make_float2(0.f, 0.f);
            accB[i][j] = make_float2(0.f, 0.f);
        }
    float2 huw[4] = {make_float2(0,0), make_float2(0,0), make_float2(0,0), make_float2(0,0)};
    float2 tracc  = make_float2(0.f, 0.f);

    const float* hbase = chan + ((t4 * 4 + r4) << 8) + (fbase << 4);

    #pragma unroll 1
    for (int fi = 0; fi < 4; ++fi) {
        const int f = fbase + fi;
        const float4 ca = *(const float4*)(hbase + (fi << 4) + 0);
        const float4 cb = *(const float4*)(hbase + (fi << 4) + 4);
        const float4 ci = *(const float4*)(hbase + (fi << 4) + 8);
        const float4 cd = *(const float4*)(hbase + (fi << 4) + 12);

        const float4* U0p = (const float4*)&sv.in.U[r4 * 258 + (f << 3)];        // d=0
        const float4* U1p = (const float4*)&sv.in.U[r4 * 258 + ((16 + f) << 3)]; // d=1
        const float4 u0q0 = U0p[0], u0q1 = U0p[1], u0q2 = U0p[2], u0q3 = U0p[3];
        const float4 u1q0 = U1p[0], u1q1 = U1p[1], u1q2 = U1p[2], u1q3 = U1p[3];

        // partials: val0[k] = conj(H)*U (d=0, m=k), val1[k] (d=1, m=8+k)
        float2 val0[8], val1[8];
        #define MK2(K, HR, HI, U0R, U0I, U1R, U1I) \
            val0[K] = make_float2((HR)*(U0R) + (HI)*(U0I), (HR)*(U0I) - (HI)*(U0R)); \
            val1[K] = make_float2((HR)*(U1R) + (HI)*(U1I), (HR)*(U1I) - (HI)*(U1R));
        MK2(0, ca.x, ci.x, u0q0.x, u0q0.y, u1q0.x, u1q0.y)
        MK2(1, ca.y, ci.y, u0q0.z, u0q0.w, u1q0.z, u1q0.w)
        MK2(2, ca.z, ci.z, u0q1.x, u0q1.y, u1q1.x, u1q1.y)
        MK2(3, ca.w, ci.w, u0q1.z, u0q1.w, u1q1.z, u1q1.w)
        MK2(4, cb.x, cd.x, u0q2.x, u0q2.y, u1q2.x, u1q2.y)
        MK2(5, cb.y, cd.y, u0q2.z, u0q2.w, u1q2.z, u1q2.w)
        MK2(6, cb.z, cd.z, u0q3.x, u0q3.y, u1q3.x, u1q3.y)
        MK2(7, cb.w, cd.w, u0q3.z, u0q3.w, u1q3.z, u1q3.w)
        #undef MK2

        // stage 1 (xor 1): keep k in {4*bit0 .. 4*bit0+3}
        float2 s1d0[4], s1d1[4];
        #pragma unroll
        for (int q = 0; q < 4; ++q) {
            float2 k0 = bit0 ? val0[4 + q] : val0[q];
            float2 n0 = bit0 ? val0[q]     : val0[4 + q];
            float2 k1 = bit0 ? val1[4 + q] : val1[q];
            float2 n1 = bit0 ? val1[q]     : val1[4 + q];
            n0.x = __shfl_xor(n0.x, 1); n0.y = __shfl_xor(n0.y, 1);
            n1.x = __shfl_xor(n1.x, 1); n1.y = __shfl_xor(n1.y, 1);
            s1d0[q] = make_float2(k0.x + n0.x, k0.y + n0.y);
            s1d1[q] = make_float2(k1.x + n1.x, k1.y + n1.y);
        }
        // stage 2 (xor 2): keep q in {2*bit1, 2*bit1+1} -> hh[kkb+jj]
        float2 h0[2], h1[2];
        #pragma unroll
        for (int jj = 0; jj < 2; ++jj) {
            float2 k0 = bit1 ? s1d0[2 + jj] : s1d0[jj];
            float2 n0 = bit1 ? s1d0[jj]     : s1d0[2 + jj];
            float2 k1 = bit1 ? s1d1[2 + jj] : s1d1[jj];
            float2 n1 = bit1 ? s1d1[jj]     : s1d1[2 + jj];
            n0.x = __shfl_xor(n0.x, 2); n0.y = __shfl_xor(n0.y, 2);
            n1.x = __shfl_xor(n1.x, 2); n1.y = __shfl_xor(n1.y, 2);
            h0[jj] = make_float2(k0.x + n0.x, k0.y + n0.y);
            h1[jj] = make_float2(k1.x + n1.x, k1.y + n1.y);
        }

        // tr_UWU partial (128 lanes per group; wave-uniform branch)
        if (lt < 128) {
            float w   = sv.in.W[((tr_d * 2 + tr_e) * 16 + f) * 8 + tr_k];
            float2 u1 = sv.in.U[tr_r * 258 + ((tr_d * 16 + f) << 3) + tr_k];
            float2 u2 = sv.in.U[tr_r * 258 + ((tr_e * 16 + f) << 3) + tr_k];
            tracc.x += w * (u1.x * u2.x + u1.y * u2.y);
            tracc.y += w * (u1.y * u2.x - u1.x * u2.y);
        }

        // T pairs + H pairs (b128 writes, m-pair rows)
        const int p = fi & 1;
        #pragma unroll
        for (int e = 0; e < 2; ++e) {
            float w0a = sv.in.W[(e * 16 + f) * 8 + kkb];
            float w0b = sv.in.W[(e * 16 + f) * 8 + kkb + 1];
            float w1a = sv.in.W[((2 + e) * 16 + f) * 8 + kkb];
            float w1b = sv.in.W[((2 + e) * 16 + f) * 8 + kkb + 1];
            float2 tva = make_float2(h0[0].x * w0a + h1[0].x * w1a,
                                     h0[0].y * w0a + h1[0].y * w1a);
            float2 tvb = make_float2(h0[1].x * w0b + h1[1].x * w1b,
                                     h0[1].y * w0b + h1[1].y * w1b);
            sh.p1.TtP[p][grp][e * 4 + mpb][t4] = make_float4(tva.x, tva.y, tvb.x, tvb.y);
            huw[e * 2 + 0].x += tva.x; huw[e * 2 + 0].y += tva.y;
            huw[e * 2 + 1].x += tvb.x; huw[e * 2 + 1].y += tvb.y;
        }
        sh.p1.HtP[p][grp][mpb][t4]     = make_float4(h0[0].x, h0[0].y, h0[1].x, h0[1].y);
        sh.p1.HtP[p][grp][4 + mpb][t4] = make_float4(h1[0].x, h1[0].y, h1[1].x, h1[1].y);
        __syncthreads();

        // quad: accA/accB [i][j] over m-pairs (b128 reads, broadcast-friendly)
        #pragma unroll
        for (int mp = 0; mp < 8; ++mp) {
            float4 tq[4], hq[4];
            #pragma unroll
            for (int i = 0; i < 4; ++i) tq[i] = sh.p1.TtP[p][grp][mp][a + 16 * i];
            #pragma unroll
            for (int j = 0; j < 4; ++j) hq[j] = sh.p1.HtP[p][grp][mp][bb + 16 * j];
            #pragma unroll
            for (int i = 0; i < 4; ++i)
                #pragma unroll
                for (int j = 0; j < 4; ++j) {
                    float2 va = accA[i][j], vb = accB[i][j];
                    va.x = fmaf(tq[i].x, hq[j].x, va.x);
                    va.y = fmaf(tq[i].x, hq[j].y, va.y);
                    vb.x = fmaf(tq[i].y, hq[j].x, vb.x);
                    vb.y = fmaf(tq[i].y, hq[j].y, vb.y);
                    va.x = fmaf(tq[i].z, hq[j].z, va.x);
                    va.y = fmaf(tq[i].z, hq[j].w, va.y);
                    vb.x = fmaf(tq[i].w, hq[j].z, vb.x);
                    vb.y = fmaf(tq[i].w, hq[j].w, vb.y);
                    accA[i][j] = va; accB[i][j] = vb;
                }
        }
    }

    // ---- tr_UWU block reduction (barrier also retires last TtP reads) ----
    #pragma unroll
    for (int off = 32; off; off >>= 1) {
        tracc.x += __shfl_xor(tracc.x, off);
        tracc.y += __shfl_xor(tracc.y, off);
    }
    if ((tid & 63) == 0) redbuf[wv] = tracc;
    __syncthreads();
    float2 trv = make_float2(0.f, 0.f);
    #pragma unroll
    for (int w = 0; w < 16; ++w) { trv.x += redbuf[w].x; trv.y += redbuf[w].y; }
    trv.x *= 0.1f; trv.y *= 0.1f;

    // ---- pair-tree merge of the 4 f-quarter partials ----
    // qacc = (accA.x + accB.y, accB.x - accA.y)
    if ((grp & 1) == 0) {                            // g0 -> AugA, g2 -> AugB
        float2 (*Dst)[SAUG] = (grp == 0) ? sh.aug.A : sh.aug.B;
        #pragma unroll
        for (int i = 0; i < 4; ++i)
            #pragma unroll
            for (int j = 0; j < 4; ++j) {
                Dst[a + 16 * i][bb + 16 * j] =
                    make_float2(accA[i][j].x + accB[i][j].y,
                                accB[i][j].x - accA[i][j].y);
            }
        #pragma unroll
        for (int e = 0; e < 2; ++e)
            #pragma unroll
            for (int jj = 0; jj < 2; ++jj)
                Dst[t4][64 + e * 8 + kkb + jj] = huw[e * 2 + jj];
    }
    __syncthreads();
    if (grp & 1) {                                   // g1 RMW AugA, g3 RMW AugB
        float2 (*Dst)[SAUG] = (grp == 1) ? sh.aug.A : sh.aug.B;
        #pragma unroll
        for (int i = 0; i < 4; ++i)
            #pragma unroll
            for (int j = 0; j < 4; ++j) {
                float2 v = Dst[a + 16 * i][bb + 16 * j];
                v.x += accA[i][j].x + accB[i][j].y;
                v.y += accB[i][j].x - accA[i][j].y;
                Dst[a + 16 * i][bb + 16 * j] = v;
            }
        #pragma unroll
        for (int e = 0; e < 2; ++e)
            #pragma unroll
            for (int jj = 0; jj < 2; ++jj) {
                int col = 64 + e * 8 + kkb + jj;
                float2 v = Dst[t4][col];
                v.x += huw[e * 2 + jj].x; v.y += huw[e * 2 + jj].y;
                Dst[t4][col] = v;
            }
    }
    __syncthreads();

    // ---- combine A+B (+trv on diag) straight into GJ registers ----
    const int gi = tid >> 4, gc = tid & 15;          // 64 rows x 16 col-slices
    const int cb = gc * 5;                           // 5 cols per thread
    const int lanebase = (tid & 63) & 48;

    float2 xr[5];
    #pragma unroll
    for (int c = 0; c < 5; ++c) {
        float2 v = sh.aug.A[gi][cb + c];
        float2 w = sh.aug.B[gi][cb + c];
        v.x += w.x; v.y += w.y;
        if (gi == cb + c) { v.x += trv.x; v.y += trv.y; }
        xr[c] = v;
    }
    if (gi == 0) {
        #pragma unroll
        for (int c = 0; c < 5; ++c) prow[0][cb + c] = xr[c];
    }
    __syncthreads();

    // ---- Gauss-Jordan: register-resident rows, diagonal pivots ----
    float2 myipv = make_float2(0.f, 0.f);

    #pragma unroll 1
    for (int ks = 0; ks < 64; ++ks) {
        const int pb = ks & 1;
        float2 pr[5];
        #pragma unroll
        for (int c = 0; c < 5; ++c) pr[c] = prow[pb][cb + c];

        float2 z = prow[pb][ks];
        float  zi = 1.0f / (z.x * z.x + z.y * z.y);
        float2 ipv = make_float2(z.x * zi, -z.y * zi);

        float2 cand = make_float2(0.f, 0.f);
        #pragma unroll
        for (int c = 0; c < 5; ++c)
            if (cb + c == ks) cand = xr[c];
        int srcl = lanebase + (ks / 5);
        float2 Lv;
        Lv.x = __shfl(cand.x, srcl);
        Lv.y = __shfl(cand.y, srcl);

        if (gi == ks) {
            myipv = ipv;
        } else {
            float2 L = cmul(Lv, ipv);
            #pragma unroll
            for (int c = 0; c < 5; ++c) {
                xr[c].x -= L.x * pr[c].x - L.y * pr[c].y;
                xr[c].y -= L.x * pr[c].y + L.y * pr[c].x;
            }
        }
        if (gi == ks + 1) {
            #pragma unroll
            for (int c = 0; c < 5; ++c) prow[pb ^ 1][cb + c] = xr[c];
        }
        __syncthreads();
    }

    // ---- extract solution (cols 64..79), normalize, write ----
    float ss = 0.f;
    if (gc >= 12) {
        #pragma unroll
        for (int c = 0; c < 5; ++c) {
            int col = cb + c;
            if (col >= 64) {
                float2 xv = cmul(xr[c], myipv);
                ss += xv.x * xv.x + xv.y * xv.y;
                sv.xout[gi][col - 64] = xv;
            }
        }
    }
    #pragma unroll
    for (int off = 32; off; off >>= 1) ss += __shfl_xor(ss, off);
    if ((tid & 63) == 0) fred[wv] = ss;
    __syncthreads();
    float total = 0.f;
    #pragma unroll
    for (int w = 0; w < 16; ++w) total += fred[w];
    float invn = rsqrtf(total);
    {
        float2 v = sv.xout[tid >> 4][tid & 15];
        out[(size_t)b * 1024 + tid] = make_float2(v.x * invn, v.y * invn);
    }
}

extern "C" void kernel_launch(void* const* d_in, const int* in_sizes, int n_in,
                              void* d_out, int out_size, void* d_ws, size_t ws_size,
                              hipStream_t stream) {
    const float* channel    = (const float*)d_in[0];
    const float* prediction = (const float*)d_in[1];
    int batch = in_sizes[0] / 65536;   // 256
    uw2v_kernel<<<dim3(batch), dim3(1024), 0, stream>>>(channel, prediction,
                                                        (float2*)d_out);
}

// Round 5
// 183.855 us; speedup vs baseline: 1.3594x; 1.3568x over previous
//
#include <hip/hip_runtime.h>
#include <math.h>

// NT=64, NR=4, DK=2, KU=8, BR=16, BATCH=256
// channel:    [B][64][4][16][16] f32 (last dim: 8 re, 8 im)
// prediction: [B][2560] = U[4][2][16][16] ++ W[2][2][16][8]
// out:        [B][64][2][8][2] f32
//
// R13: two-kernel split. R9-R12 proved the 1024-thread monolith always
// gets a 64-VGPR budget (attributes ignored) -> 272MB spill. Facts kept:
// 512-thread blocks compile this code to 120 VGPR, no spill (R8).
//  - uw2v_build: 512 blocks x 512 threads (2 per batch, half the f-range
//    each; 2 groups x 256 threads x 4 fi). LDS 77KB, VGPR ~120 -> 2
//    blocks/CU = 4 waves/SIMD. Writes partial Aug (64x80) + raw tr
//    partial to workspace (exact: diag term is linear in partials).
//  - uw2v_gj: 256 blocks x 1024 threads, 16 thr/row x 5 cols. GJ pressure
//    ~40 VGPR fits the 64-budget -> no spill, 4 waves/SIMD, half the
//    per-pivot critical-path work vs R8's 8x10.
// Workspace: 512*40960 B Aug partials + 512*8 B tr partials ~ 21 MB.

#define SAUG 84   // float2 stride of Aug rows
#define STP  65   // float4 stride of paired TtP/HtP rows

namespace {
union alignas(16) ShU {
    struct { float4 TtP[2][2][8][STP]; float4 HtP[2][2][8][STP]; } p1; // 66560 B
    float2 Aug[64][SAUG];                                              // 43008 B
};
struct alignas(16) ShV {
    float2 U[4 * 258];
    float  W[512];
};
}

__device__ __forceinline__ float2 cmul(float2 x, float2 y) {
    return make_float2(x.x * y.x - x.y * y.y, x.x * y.y + x.y * y.x);
}

// ---------------------------------------------------------------- build ----
__global__ __launch_bounds__(512, 1)
void uw2v_build(const float* __restrict__ channel,
                const float* __restrict__ prediction,
                float2* __restrict__ wsAug,
                float2* __restrict__ wsTr)
{
    __shared__ ShU sh;
    __shared__ ShV sv;
    __shared__ float2 redbuf[8];

    const int bid = blockIdx.x;
    const int b   = bid >> 1;
    const int hf  = bid & 1;                         // f-half owned by this block
    const int tid = threadIdx.x;
    const int wv  = tid >> 6;
    const float* pred = prediction + (size_t)b * 2560;
    const float* chan = channel + (size_t)b * 65536;

    // ---- load U (re/im merged, padded per-r stride) and W ----
    #pragma unroll
    for (int i = 0; i < 2; ++i) {
        int m = tid + i * 512;                       // [r][d][f][k]
        int r = m >> 8, d = (m >> 7) & 1, f = (m >> 3) & 15, k = m & 7;
        const float* src = pred + (((r * 2 + d) * 16 + f) << 4);
        sv.U[r * 258 + ((d * 16 + f) << 3) + k] = make_float2(src[k], src[k + 8]);
    }
    sv.W[tid] = pred[2048 + tid];
    __syncthreads();

    const int grp2 = tid >> 8;                       // local f-quarter 0/1
    const int lt   = tid & 255;
    const int t4 = lt >> 2, r4 = lt & 3;
    const int a  = lt >> 4, bb = lt & 15;
    const int bit0 = r4 & 1, bit1 = (r4 >> 1) & 1;
    const int kkb  = 4 * bit0 + 2 * bit1;            // owned k-slice base (even)
    const int mpb  = kkb >> 1;                       // owned m-pair row (0..3)
    const int fbase = ((hf << 1) | grp2) << 2;       // global f-quarter * 4
    const int tr_r = lt >> 5, tr_d = (lt >> 4) & 1, tr_e = (lt >> 3) & 1, tr_k = lt & 7;

    // split accumulators: accA = sum t_re*h, accB = sum t_im*h (h = (re,im))
    float2 accA[4][4], accB[4][4];
    #pragma unroll
    for (int i = 0; i < 4; ++i)
        #pragma unroll
        for (int j = 0; j < 4; ++j) {
            accA[i][j] = make_float2(0.f, 0.f);
            accB[i][j] = make_float2(0.f, 0.f);
        }
    float2 huw[4] = {make_float2(0,0), make_float2(0,0), make_float2(0,0), make_float2(0,0)};
    float2 tracc  = make_float2(0.f, 0.f);

    const float* hbase = chan + ((t4 * 4 + r4) << 8) + (fbase << 4);

    #pragma unroll 1
    for (int fi = 0; fi < 4; ++fi) {
        const int f = fbase + fi;
        const float4 ca = *(const float4*)(hbase + (fi << 4) + 0);
        const float4 cb = *(const float4*)(hbase + (fi << 4) + 4);
        const float4 ci = *(const float4*)(hbase + (fi << 4) + 8);
        const float4 cd = *(const float4*)(hbase + (fi << 4) + 12);

        const float4* U0p = (const float4*)&sv.U[r4 * 258 + (f << 3)];        // d=0
        const float4* U1p = (const float4*)&sv.U[r4 * 258 + ((16 + f) << 3)]; // d=1
        const float4 u0q0 = U0p[0], u0q1 = U0p[1], u0q2 = U0p[2], u0q3 = U0p[3];
        const float4 u1q0 = U1p[0], u1q1 = U1p[1], u1q2 = U1p[2], u1q3 = U1p[3];

        // partials: val0[k] = conj(H)*U (d=0, m=k), val1[k] (d=1, m=8+k)
        float2 val0[8], val1[8];
        #define MK2(K, HR, HI, U0R, U0I, U1R, U1I) \
            val0[K] = make_float2((HR)*(U0R) + (HI)*(U0I), (HR)*(U0I) - (HI)*(U0R)); \
            val1[K] = make_float2((HR)*(U1R) + (HI)*(U1I), (HR)*(U1I) - (HI)*(U1R));
        MK2(0, ca.x, ci.x, u0q0.x, u0q0.y, u1q0.x, u1q0.y)
        MK2(1, ca.y, ci.y, u0q0.z, u0q0.w, u1q0.z, u1q0.w)
        MK2(2, ca.z, ci.z, u0q1.x, u0q1.y, u1q1.x, u1q1.y)
        MK2(3, ca.w, ci.w, u0q1.z, u0q1.w, u1q1.z, u1q1.w)
        MK2(4, cb.x, cd.x, u0q2.x, u0q2.y, u1q2.x, u1q2.y)
        MK2(5, cb.y, cd.y, u0q2.z, u0q2.w, u1q2.z, u1q2.w)
        MK2(6, cb.z, cd.z, u0q3.x, u0q3.y, u1q3.x, u1q3.y)
        MK2(7, cb.w, cd.w, u0q3.z, u0q3.w, u1q3.z, u1q3.w)
        #undef MK2

        // stage 1 (xor 1): keep k in {4*bit0 .. 4*bit0+3}
        float2 s1d0[4], s1d1[4];
        #pragma unroll
        for (int q = 0; q < 4; ++q) {
            float2 k0 = bit0 ? val0[4 + q] : val0[q];
            float2 n0 = bit0 ? val0[q]     : val0[4 + q];
            float2 k1 = bit0 ? val1[4 + q] : val1[q];
            float2 n1 = bit0 ? val1[q]     : val1[4 + q];
            n0.x = __shfl_xor(n0.x, 1); n0.y = __shfl_xor(n0.y, 1);
            n1.x = __shfl_xor(n1.x, 1); n1.y = __shfl_xor(n1.y, 1);
            s1d0[q] = make_float2(k0.x + n0.x, k0.y + n0.y);
            s1d1[q] = make_float2(k1.x + n1.x, k1.y + n1.y);
        }
        // stage 2 (xor 2): keep q in {2*bit1, 2*bit1+1} -> hh[kkb+jj]
        float2 h0[2], h1[2];
        #pragma unroll
        for (int jj = 0; jj < 2; ++jj) {
            float2 k0 = bit1 ? s1d0[2 + jj] : s1d0[jj];
            float2 n0 = bit1 ? s1d0[jj]     : s1d0[2 + jj];
            float2 k1 = bit1 ? s1d1[2 + jj] : s1d1[jj];
            float2 n1 = bit1 ? s1d1[jj]     : s1d1[2 + jj];
            n0.x = __shfl_xor(n0.x, 2); n0.y = __shfl_xor(n0.y, 2);
            n1.x = __shfl_xor(n1.x, 2); n1.y = __shfl_xor(n1.y, 2);
            h0[jj] = make_float2(k0.x + n0.x, k0.y + n0.y);
            h1[jj] = make_float2(k1.x + n1.x, k1.y + n1.y);
        }

        // tr_UWU partial (128 lanes per group; wave-uniform branch)
        if (lt < 128) {
            float w   = sv.W[((tr_d * 2 + tr_e) * 16 + f) * 8 + tr_k];
            float2 u1 = sv.U[tr_r * 258 + ((tr_d * 16 + f) << 3) + tr_k];
            float2 u2 = sv.U[tr_r * 258 + ((tr_e * 16 + f) << 3) + tr_k];
            tracc.x += w * (u1.x * u2.x + u1.y * u2.y);
            tracc.y += w * (u1.y * u2.x - u1.x * u2.y);
        }

        // T pairs + H pairs (b128 writes, m-pair rows)
        const int p = fi & 1;
        #pragma unroll
        for (int e = 0; e < 2; ++e) {
            float w0a = sv.W[(e * 16 + f) * 8 + kkb];
            float w0b = sv.W[(e * 16 + f) * 8 + kkb + 1];
            float w1a = sv.W[((2 + e) * 16 + f) * 8 + kkb];
            float w1b = sv.W[((2 + e) * 16 + f) * 8 + kkb + 1];
            float2 tva = make_float2(h0[0].x * w0a + h1[0].x * w1a,
                                     h0[0].y * w0a + h1[0].y * w1a);
            float2 tvb = make_float2(h0[1].x * w0b + h1[1].x * w1b,
                                     h0[1].y * w0b + h1[1].y * w1b);
            sh.p1.TtP[p][grp2][e * 4 + mpb][t4] = make_float4(tva.x, tva.y, tvb.x, tvb.y);
            huw[e * 2 + 0].x += tva.x; huw[e * 2 + 0].y += tva.y;
            huw[e * 2 + 1].x += tvb.x; huw[e * 2 + 1].y += tvb.y;
        }
        sh.p1.HtP[p][grp2][mpb][t4]     = make_float4(h0[0].x, h0[0].y, h0[1].x, h0[1].y);
        sh.p1.HtP[p][grp2][4 + mpb][t4] = make_float4(h1[0].x, h1[0].y, h1[1].x, h1[1].y);
        __syncthreads();

        // quad: accA/accB [i][j] over m-pairs (b128 reads, broadcast-friendly)
        #pragma unroll
        for (int mp = 0; mp < 8; ++mp) {
            float4 tq[4], hq[4];
            #pragma unroll
            for (int i = 0; i < 4; ++i) tq[i] = sh.p1.TtP[p][grp2][mp][a + 16 * i];
            #pragma unroll
            for (int j = 0; j < 4; ++j) hq[j] = sh.p1.HtP[p][grp2][mp][bb + 16 * j];
            #pragma unroll
            for (int i = 0; i < 4; ++i)
                #pragma unroll
                for (int j = 0; j < 4; ++j) {
                    float2 va = accA[i][j], vb = accB[i][j];
                    va.x = fmaf(tq[i].x, hq[j].x, va.x);
                    va.y = fmaf(tq[i].x, hq[j].y, va.y);
                    vb.x = fmaf(tq[i].y, hq[j].x, vb.x);
                    vb.y = fmaf(tq[i].y, hq[j].y, vb.y);
                    va.x = fmaf(tq[i].z, hq[j].z, va.x);
                    va.y = fmaf(tq[i].z, hq[j].w, va.y);
                    vb.x = fmaf(tq[i].w, hq[j].z, vb.x);
                    vb.y = fmaf(tq[i].w, hq[j].w, vb.y);
                    accA[i][j] = va; accB[i][j] = vb;
                }
        }
    }

    // ---- tr_UWU block reduction (barrier also retires last TtP reads) ----
    #pragma unroll
    for (int off = 32; off; off >>= 1) {
        tracc.x += __shfl_xor(tracc.x, off);
        tracc.y += __shfl_xor(tracc.y, off);
    }
    if ((tid & 63) == 0) redbuf[wv] = tracc;
    __syncthreads();
    if (tid == 0) {
        float2 s = make_float2(0.f, 0.f);
        #pragma unroll
        for (int w = 0; w < 8; ++w) { s.x += redbuf[w].x; s.y += redbuf[w].y; }
        wsTr[bid] = s;                               // raw partial (scale in GJ)
    }

    // ---- merge 2 group partials into Aug = [quad | HUW] (no diag yet) ----
    // qacc = (accA.x + accB.y, accB.x - accA.y)
    if (grp2 == 0) {
        #pragma unroll
        for (int i = 0; i < 4; ++i)
            #pragma unroll
            for (int j = 0; j < 4; ++j)
                sh.Aug[a + 16 * i][bb + 16 * j] =
                    make_float2(accA[i][j].x + accB[i][j].y,
                                accB[i][j].x - accA[i][j].y);
        #pragma unroll
        for (int e = 0; e < 2; ++e)
            #pragma unroll
            for (int jj = 0; jj < 2; ++jj)
                sh.Aug[t4][64 + e * 8 + kkb + jj] = huw[e * 2 + jj];
    }
    __syncthreads();
    if (grp2 == 1) {
        #pragma unroll
        for (int i = 0; i < 4; ++i)
            #pragma unroll
            for (int j = 0; j < 4; ++j) {
                float2 v = sh.Aug[a + 16 * i][bb + 16 * j];
                v.x += accA[i][j].x + accB[i][j].y;
                v.y += accB[i][j].x - accA[i][j].y;
                sh.Aug[a + 16 * i][bb + 16 * j] = v;
            }
        #pragma unroll
        for (int e = 0; e < 2; ++e)
            #pragma unroll
            for (int jj = 0; jj < 2; ++jj) {
                int col = 64 + e * 8 + kkb + jj;
                float2 v = sh.Aug[t4][col];
                v.x += huw[e * 2 + jj].x; v.y += huw[e * 2 + jj].y;
                sh.Aug[t4][col] = v;
            }
    }
    __syncthreads();

    // ---- write partial Aug (64x80 float2, b128) to workspace ----
    {
        const int row = tid >> 3, q = tid & 7;       // 8 threads/row, 10 cols each
        const float4* src = (const float4*)&sh.Aug[row][q * 10];
        float4* dst = (float4*)(wsAug + (size_t)bid * 5120 + row * 80 + q * 10);
        #pragma unroll
        for (int j = 0; j < 5; ++j) dst[j] = src[j];
    }
}

// ------------------------------------------------------------------- GJ ----
__global__ __launch_bounds__(1024)
void uw2v_gj(const float2* __restrict__ wsAug,
             const float2* __restrict__ wsTr,
             float2* __restrict__ out)
{
    __shared__ alignas(16) float2 prow[2][80];   // pivot-row double buffer
    __shared__ float2 xout[64][17];
    __shared__ float  fred[16];

    const int b   = blockIdx.x;
    const int tid = threadIdx.x;
    const int wv  = tid >> 6;

    const float2 tA = wsTr[2 * b], tB = wsTr[2 * b + 1];
    const float2 trv = make_float2((tA.x + tB.x) * 0.1f, (tA.y + tB.y) * 0.1f);

    const int gi = tid >> 4, gc = tid & 15;          // 64 rows x 16 col-slices
    const int cb = gc * 5;                           // 5 cols per thread
    const int lanebase = (tid & 63) & 48;

    const float2* A0 = wsAug + (size_t)(2 * b) * 5120 + gi * 80;
    const float2* A1 = wsAug + (size_t)(2 * b + 1) * 5120 + gi * 80;

    float2 xr[5];
    #pragma unroll
    for (int c = 0; c < 5; ++c) {
        float2 v = A0[cb + c];
        float2 w = A1[cb + c];
        v.x += w.x; v.y += w.y;
        if (gi == cb + c) { v.x += trv.x; v.y += trv.y; }
        xr[c] = v;
    }
    if (gi == 0) {
        #pragma unroll
        for (int c = 0; c < 5; ++c) prow[0][cb + c] = xr[c];
    }
    __syncthreads();

    // ---- Gauss-Jordan: register-resident rows, diagonal pivots ----
    float2 myipv = make_float2(0.f, 0.f);

    #pragma unroll 1
    for (int ks = 0; ks < 64; ++ks) {
        const int pb = ks & 1;
        float2 pr[5];
        #pragma unroll
        for (int c = 0; c < 5; ++c) pr[c] = prow[pb][cb + c];

        float2 z = prow[pb][ks];
        float  zi = 1.0f / (z.x * z.x + z.y * z.y);
        float2 ipv = make_float2(z.x * zi, -z.y * zi);

        float2 cand = make_float2(0.f, 0.f);
        #pragma unroll
        for (int c = 0; c < 5; ++c)
            if (cb + c == ks) cand = xr[c];
        int srcl = lanebase + (ks / 5);
        float2 Lv;
        Lv.x = __shfl(cand.x, srcl);
        Lv.y = __shfl(cand.y, srcl);

        if (gi == ks) {
            myipv = ipv;
        } else {
            float2 L = cmul(Lv, ipv);
            #pragma unroll
            for (int c = 0; c < 5; ++c) {
                xr[c].x -= L.x * pr[c].x - L.y * pr[c].y;
                xr[c].y -= L.x * pr[c].y + L.y * pr[c].x;
            }
        }
        if (gi == ks + 1) {
            #pragma unroll
            for (int c = 0; c < 5; ++c) prow[pb ^ 1][cb + c] = xr[c];
        }
        __syncthreads();
    }

    // ---- extract solution (cols 64..79), normalize, write ----
    float ss = 0.f;
    if (gc >= 12) {
        #pragma unroll
        for (int c = 0; c < 5; ++c) {
            int col = cb + c;
            if (col >= 64) {
                float2 xv = cmul(xr[c], myipv);
                ss += xv.x * xv.x + xv.y * xv.y;
                xout[gi][col - 64] = xv;
            }
        }
    }
    #pragma unroll
    for (int off = 32; off; off >>= 1) ss += __shfl_xor(ss, off);
    if ((tid & 63) == 0) fred[wv] = ss;
    __syncthreads();
    float total = 0.f;
    #pragma unroll
    for (int w = 0; w < 16; ++w) total += fred[w];
    float invn = rsqrtf(total);
    {
        float2 v = xout[tid >> 4][tid & 15];
        out[(size_t)b * 1024 + tid] = make_float2(v.x * invn, v.y * invn);
    }
}

extern "C" void kernel_launch(void* const* d_in, const int* in_sizes, int n_in,
                              void* d_out, int out_size, void* d_ws, size_t ws_size,
                              hipStream_t stream) {
    const float* channel    = (const float*)d_in[0];
    const float* prediction = (const float*)d_in[1];
    int batch = in_sizes[0] / 65536;   // 256
    // workspace: [batch*2][64][80] float2 Aug partials, then [batch*2] float2 tr
    float2* wsAug = (float2*)d_ws;
    float2* wsTr  = wsAug + (size_t)batch * 2 * 5120;
    uw2v_build<<<dim3(batch * 2), dim3(512), 0, stream>>>(channel, prediction,
                                                          wsAug, wsTr);
    uw2v_gj<<<dim3(batch), dim3(1024), 0, stream>>>(wsAug, wsTr, (float2*)d_out);
}

// Round 6
// 180.089 us; speedup vs baseline: 1.3878x; 1.0209x over previous
//
#include <hip/hip_runtime.h>
#include <math.h>

// NT=64, NR=4, DK=2, KU=8, BR=16, BATCH=256
// channel:    [B][64][4][16][16] f32 (last dim: 8 re, 8 im)
// prediction: [B][2560] = U[4][2][16][16] ++ W[2][2][16][8]
// out:        [B][64][2][8][2] f32
//
// R14 = R13 two-kernel split + two fixes:
//  (a) build: single-buffered TtP/HtP (extra barrier per fi) -> LDS union
//      drops 77KB -> 52.4KB. R13's 2x77KB=154.6KB apparently missed the
//      160KB pool after driver rounding (occupancy 18%, dur = 2x serial
//      rounds). 2x52.4KB = 105KB leaves huge margin -> 2 blocks/CU.
//  (b) GJ: 4-pivot panel chunks. Wave w owns rows 4w..4w+3 (16 thr/row),
//      so a 4-pivot cascade is wave-local (shfl, no barrier). Owner wave
//      publishes 4 raw pivot rows + ipv[4]; other waves eliminate 4 cols
//      per barrier interval (panel mutually orthogonalized -> L factors
//      independent). Pipelined: wave c+1 eliminates then cascades in the
//      same interval. 17 barriers vs 64.

#define SAUG 82   // float2 stride of Aug rows (odd-dword stride, 16B-aligned rows)
#define STP  65   // float4 stride of TtP/HtP rows

namespace {
union alignas(16) ShU {
    struct { float4 TtP[2][8][STP]; float4 HtP[2][8][STP]; } p1;  // 33280 B
    float2 Aug[64][SAUG];                                         // 41984 B
};
struct alignas(16) ShV {
    float2 U[4 * 258];
    float  W[512];
};
}

__device__ __forceinline__ float2 cmul(float2 x, float2 y) {
    return make_float2(x.x * y.x - x.y * y.y, x.x * y.y + x.y * y.x);
}

// ---------------------------------------------------------------- build ----
__global__ __launch_bounds__(512, 1)
void uw2v_build(const float* __restrict__ channel,
                const float* __restrict__ prediction,
                float2* __restrict__ wsAug,
                float2* __restrict__ wsTr)
{
    __shared__ ShU sh;
    __shared__ ShV sv;
    __shared__ float2 redbuf[8];

    const int bid = blockIdx.x;
    const int b   = bid >> 1;
    const int hf  = bid & 1;                         // f-half owned by this block
    const int tid = threadIdx.x;
    const int wv  = tid >> 6;
    const float* pred = prediction + (size_t)b * 2560;
    const float* chan = channel + (size_t)b * 65536;

    // ---- load U (re/im merged, padded per-r stride) and W ----
    #pragma unroll
    for (int i = 0; i < 2; ++i) {
        int m = tid + i * 512;                       // [r][d][f][k]
        int r = m >> 8, d = (m >> 7) & 1, f = (m >> 3) & 15, k = m & 7;
        const float* src = pred + (((r * 2 + d) * 16 + f) << 4);
        sv.U[r * 258 + ((d * 16 + f) << 3) + k] = make_float2(src[k], src[k + 8]);
    }
    sv.W[tid] = pred[2048 + tid];
    __syncthreads();

    const int grp2 = tid >> 8;                       // local f-quarter 0/1
    const int lt   = tid & 255;
    const int t4 = lt >> 2, r4 = lt & 3;
    const int a  = lt >> 4, bb = lt & 15;
    const int bit0 = r4 & 1, bit1 = (r4 >> 1) & 1;
    const int kkb  = 4 * bit0 + 2 * bit1;            // owned k-slice base (even)
    const int mpb  = kkb >> 1;                       // owned m-pair row (0..3)
    const int fbase = ((hf << 1) | grp2) << 2;       // global f-quarter * 4
    const int tr_r = lt >> 5, tr_d = (lt >> 4) & 1, tr_e = (lt >> 3) & 1, tr_k = lt & 7;

    // split accumulators: accA = sum t_re*h, accB = sum t_im*h (h = (re,im))
    float2 accA[4][4], accB[4][4];
    #pragma unroll
    for (int i = 0; i < 4; ++i)
        #pragma unroll
        for (int j = 0; j < 4; ++j) {
            accA[i][j] = make_float2(0.f, 0.f);
            accB[i][j] = make_float2(0.f, 0.f);
        }
    float2 huw[4] = {make_float2(0,0), make_float2(0,0), make_float2(0,0), make_float2(0,0)};
    float2 tracc  = make_float2(0.f, 0.f);

    const float* hbase = chan + ((t4 * 4 + r4) << 8) + (fbase << 4);

    #pragma unroll 1
    for (int fi = 0; fi < 4; ++fi) {
        const int f = fbase + fi;
        const float4 ca = *(const float4*)(hbase + (fi << 4) + 0);
        const float4 cb = *(const float4*)(hbase + (fi << 4) + 4);
        const float4 ci = *(const float4*)(hbase + (fi << 4) + 8);
        const float4 cd = *(const float4*)(hbase + (fi << 4) + 12);

        const float4* U0p = (const float4*)&sv.U[r4 * 258 + (f << 3)];        // d=0
        const float4* U1p = (const float4*)&sv.U[r4 * 258 + ((16 + f) << 3)]; // d=1
        const float4 u0q0 = U0p[0], u0q1 = U0p[1], u0q2 = U0p[2], u0q3 = U0p[3];
        const float4 u1q0 = U1p[0], u1q1 = U1p[1], u1q2 = U1p[2], u1q3 = U1p[3];

        // partials: val0[k] = conj(H)*U (d=0, m=k), val1[k] (d=1, m=8+k)
        float2 val0[8], val1[8];
        #define MK2(K, HR, HI, U0R, U0I, U1R, U1I) \
            val0[K] = make_float2((HR)*(U0R) + (HI)*(U0I), (HR)*(U0I) - (HI)*(U0R)); \
            val1[K] = make_float2((HR)*(U1R) + (HI)*(U1I), (HR)*(U1I) - (HI)*(U1R));
        MK2(0, ca.x, ci.x, u0q0.x, u0q0.y, u1q0.x, u1q0.y)
        MK2(1, ca.y, ci.y, u0q0.z, u0q0.w, u1q0.z, u1q0.w)
        MK2(2, ca.z, ci.z, u0q1.x, u0q1.y, u1q1.x, u1q1.y)
        MK2(3, ca.w, ci.w, u0q1.z, u0q1.w, u1q1.z, u1q1.w)
        MK2(4, cb.x, cd.x, u0q2.x, u0q2.y, u1q2.x, u1q2.y)
        MK2(5, cb.y, cd.y, u0q2.z, u0q2.w, u1q2.z, u1q2.w)
        MK2(6, cb.z, cd.z, u0q3.x, u0q3.y, u1q3.x, u1q3.y)
        MK2(7, cb.w, cd.w, u0q3.z, u0q3.w, u1q3.z, u1q3.w)
        #undef MK2

        // stage 1 (xor 1): keep k in {4*bit0 .. 4*bit0+3}
        float2 s1d0[4], s1d1[4];
        #pragma unroll
        for (int q = 0; q < 4; ++q) {
            float2 k0 = bit0 ? val0[4 + q] : val0[q];
            float2 n0 = bit0 ? val0[q]     : val0[4 + q];
            float2 k1 = bit0 ? val1[4 + q] : val1[q];
            float2 n1 = bit0 ? val1[q]     : val1[4 + q];
            n0.x = __shfl_xor(n0.x, 1); n0.y = __shfl_xor(n0.y, 1);
            n1.x = __shfl_xor(n1.x, 1); n1.y = __shfl_xor(n1.y, 1);
            s1d0[q] = make_float2(k0.x + n0.x, k0.y + n0.y);
            s1d1[q] = make_float2(k1.x + n1.x, k1.y + n1.y);
        }
        // stage 2 (xor 2): keep q in {2*bit1, 2*bit1+1} -> hh[kkb+jj]
        float2 h0[2], h1[2];
        #pragma unroll
        for (int jj = 0; jj < 2; ++jj) {
            float2 k0 = bit1 ? s1d0[2 + jj] : s1d0[jj];
            float2 n0 = bit1 ? s1d0[jj]     : s1d0[2 + jj];
            float2 k1 = bit1 ? s1d1[2 + jj] : s1d1[jj];
            float2 n1 = bit1 ? s1d1[jj]     : s1d1[2 + jj];
            n0.x = __shfl_xor(n0.x, 2); n0.y = __shfl_xor(n0.y, 2);
            n1.x = __shfl_xor(n1.x, 2); n1.y = __shfl_xor(n1.y, 2);
            h0[jj] = make_float2(k0.x + n0.x, k0.y + n0.y);
            h1[jj] = make_float2(k1.x + n1.x, k1.y + n1.y);
        }

        // tr_UWU partial (128 lanes per group; wave-uniform branch)
        if (lt < 128) {
            float w   = sv.W[((tr_d * 2 + tr_e) * 16 + f) * 8 + tr_k];
            float2 u1 = sv.U[tr_r * 258 + ((tr_d * 16 + f) << 3) + tr_k];
            float2 u2 = sv.U[tr_r * 258 + ((tr_e * 16 + f) << 3) + tr_k];
            tracc.x += w * (u1.x * u2.x + u1.y * u2.y);
            tracc.y += w * (u1.y * u2.x - u1.x * u2.y);
        }

        // T pairs + H pairs (b128 writes, m-pair rows) -- single buffer
        #pragma unroll
        for (int e = 0; e < 2; ++e) {
            float w0a = sv.W[(e * 16 + f) * 8 + kkb];
            float w0b = sv.W[(e * 16 + f) * 8 + kkb + 1];
            float w1a = sv.W[((2 + e) * 16 + f) * 8 + kkb];
            float w1b = sv.W[((2 + e) * 16 + f) * 8 + kkb + 1];
            float2 tva = make_float2(h0[0].x * w0a + h1[0].x * w1a,
                                     h0[0].y * w0a + h1[0].y * w1a);
            float2 tvb = make_float2(h0[1].x * w0b + h1[1].x * w1b,
                                     h0[1].y * w0b + h1[1].y * w1b);
            sh.p1.TtP[grp2][e * 4 + mpb][t4] = make_float4(tva.x, tva.y, tvb.x, tvb.y);
            huw[e * 2 + 0].x += tva.x; huw[e * 2 + 0].y += tva.y;
            huw[e * 2 + 1].x += tvb.x; huw[e * 2 + 1].y += tvb.y;
        }
        sh.p1.HtP[grp2][mpb][t4]     = make_float4(h0[0].x, h0[0].y, h0[1].x, h0[1].y);
        sh.p1.HtP[grp2][4 + mpb][t4] = make_float4(h1[0].x, h1[0].y, h1[1].x, h1[1].y);
        __syncthreads();

        // quad: accA/accB [i][j] over m-pairs (b128 reads, broadcast-friendly)
        #pragma unroll
        for (int mp = 0; mp < 8; ++mp) {
            float4 tq[4], hq[4];
            #pragma unroll
            for (int i = 0; i < 4; ++i) tq[i] = sh.p1.TtP[grp2][mp][a + 16 * i];
            #pragma unroll
            for (int j = 0; j < 4; ++j) hq[j] = sh.p1.HtP[grp2][mp][bb + 16 * j];
            #pragma unroll
            for (int i = 0; i < 4; ++i)
                #pragma unroll
                for (int j = 0; j < 4; ++j) {
                    float2 va = accA[i][j], vb = accB[i][j];
                    va.x = fmaf(tq[i].x, hq[j].x, va.x);
                    va.y = fmaf(tq[i].x, hq[j].y, va.y);
                    vb.x = fmaf(tq[i].y, hq[j].x, vb.x);
                    vb.y = fmaf(tq[i].y, hq[j].y, vb.y);
                    va.x = fmaf(tq[i].z, hq[j].z, va.x);
                    va.y = fmaf(tq[i].z, hq[j].w, va.y);
                    vb.x = fmaf(tq[i].w, hq[j].z, vb.x);
                    vb.y = fmaf(tq[i].w, hq[j].w, vb.y);
                    accA[i][j] = va; accB[i][j] = vb;
                }
        }
        __syncthreads();   // single-buffer WAR guard before next fi's writes
    }

    // ---- tr_UWU block reduction ----
    #pragma unroll
    for (int off = 32; off; off >>= 1) {
        tracc.x += __shfl_xor(tracc.x, off);
        tracc.y += __shfl_xor(tracc.y, off);
    }
    if ((tid & 63) == 0) redbuf[wv] = tracc;
    __syncthreads();
    if (tid == 0) {
        float2 s = make_float2(0.f, 0.f);
        #pragma unroll
        for (int w = 0; w < 8; ++w) { s.x += redbuf[w].x; s.y += redbuf[w].y; }
        wsTr[bid] = s;                               // raw partial (scale in GJ)
    }

    // ---- merge 2 group partials into Aug = [quad | HUW] (no diag yet) ----
    // qacc = (accA.x + accB.y, accB.x - accA.y)
    if (grp2 == 0) {
        #pragma unroll
        for (int i = 0; i < 4; ++i)
            #pragma unroll
            for (int j = 0; j < 4; ++j)
                sh.Aug[a + 16 * i][bb + 16 * j] =
                    make_float2(accA[i][j].x + accB[i][j].y,
                                accB[i][j].x - accA[i][j].y);
        #pragma unroll
        for (int e = 0; e < 2; ++e)
            #pragma unroll
            for (int jj = 0; jj < 2; ++jj)
                sh.Aug[t4][64 + e * 8 + kkb + jj] = huw[e * 2 + jj];
    }
    __syncthreads();
    if (grp2 == 1) {
        #pragma unroll
        for (int i = 0; i < 4; ++i)
            #pragma unroll
            for (int j = 0; j < 4; ++j) {
                float2 v = sh.Aug[a + 16 * i][bb + 16 * j];
                v.x += accA[i][j].x + accB[i][j].y;
                v.y += accB[i][j].x - accA[i][j].y;
                sh.Aug[a + 16 * i][bb + 16 * j] = v;
            }
        #pragma unroll
        for (int e = 0; e < 2; ++e)
            #pragma unroll
            for (int jj = 0; jj < 2; ++jj) {
                int col = 64 + e * 8 + kkb + jj;
                float2 v = sh.Aug[t4][col];
                v.x += huw[e * 2 + jj].x; v.y += huw[e * 2 + jj].y;
                sh.Aug[t4][col] = v;
            }
    }
    __syncthreads();

    // ---- write partial Aug (64x80 float2, b128) to workspace ----
    {
        const int row = tid >> 3, q = tid & 7;       // 8 threads/row, 10 cols each
        const float4* src = (const float4*)&sh.Aug[row][q * 10];
        float4* dst = (float4*)(wsAug + (size_t)bid * 5120 + row * 80 + q * 10);
        #pragma unroll
        for (int j = 0; j < 5; ++j) dst[j] = src[j];
    }
}

// ------------------------------------------------------------------- GJ ----
// 1024 threads: 64 rows x 16 col-slices (5 cols each). Wave w owns rows
// 4w..4w+3. Chunked Gauss-Jordan: 16 chunks of 4 pivots; owner wave does a
// wave-local cascade (in-panel GJ via shfl), publishes raw pivot rows +
// ipv[4]; other waves eliminate all 4 columns per barrier interval.
__global__ __launch_bounds__(1024)
void uw2v_gj(const float2* __restrict__ wsAug,
             const float2* __restrict__ wsTr,
             float2* __restrict__ out)
{
    __shared__ alignas(16) float2 pivR[2][4][80];   // chunk pivot rows (dbuf)
    __shared__ float2 pivI[2][4];                   // chunk inverse pivots
    __shared__ float2 xout[64][17];
    __shared__ float  fred[16];

    const int b   = blockIdx.x;
    const int tid = threadIdx.x;
    const int wv  = tid >> 6;

    const float2 tA = wsTr[2 * b], tB = wsTr[2 * b + 1];
    const float2 trv = make_float2((tA.x + tB.x) * 0.1f, (tA.y + tB.y) * 0.1f);

    const int gi = tid >> 4, gc = tid & 15;          // row, col-slice
    const int cb = gc * 5;                           // 5 cols per thread
    const int lanebase = (tid & 63) & 48;            // my row's base lane in wave

    const float2* A0 = wsAug + (size_t)(2 * b) * 5120 + gi * 80;
    const float2* A1 = wsAug + (size_t)(2 * b + 1) * 5120 + gi * 80;

    float2 xr[5];
    #pragma unroll
    for (int c = 0; c < 5; ++c) {
        float2 v = A0[cb + c];
        float2 w = A1[cb + c];
        v.x += w.x; v.y += w.y;
        if (gi == cb + c) { v.x += trv.x; v.y += trv.y; }
        xr[c] = v;
    }

    float2 myipv = make_float2(0.f, 0.f);

    // wave-local cascade: in-panel GJ on my wave's 4 rows, publish to buf nb
    auto cascade = [&](int chunk, int nb) {
        #pragma unroll
        for (int p = 0; p < 4; ++p) {
            const int col = 4 * chunk + p;
            const int cs  = col / 5;                 // owning col-slice
            // z = panel row p's value at col  (broadcast from lane p*16+cs)
            float2 zc = make_float2(0.f, 0.f);
            #pragma unroll
            for (int c = 0; c < 5; ++c)
                if (cb + c == col) zc = xr[c];
            float2 z;
            z.x = __shfl(zc.x, p * 16 + cs);
            z.y = __shfl(zc.y, p * 16 + cs);
            float  zi  = 1.0f / (z.x * z.x + z.y * z.y);
            float2 ipv = make_float2(z.x * zi, -z.y * zi);
            const bool isPiv = (gi == col);
            if (isPiv) myipv = ipv;
            // Lv = my row's value at col (from my row's owning lane)
            float2 cand = make_float2(0.f, 0.f);
            #pragma unroll
            for (int c = 0; c < 5; ++c)
                if (cb + c == col) cand = xr[c];
            float2 Lv;
            Lv.x = __shfl(cand.x, lanebase + cs);
            Lv.y = __shfl(cand.y, lanebase + cs);
            // pr = pivot row p's values at my cols (from lane p*16+gc)
            float2 pr[5];
            #pragma unroll
            for (int c = 0; c < 5; ++c) {
                pr[c].x = __shfl(xr[c].x, p * 16 + gc);
                pr[c].y = __shfl(xr[c].y, p * 16 + gc);
            }
            if (!isPiv) {
                float2 L = cmul(Lv, ipv);
                #pragma unroll
                for (int c = 0; c < 5; ++c) {
                    xr[c].x -= L.x * pr[c].x - L.y * pr[c].y;
                    xr[c].y -= L.x * pr[c].y + L.y * pr[c].x;
                }
            }
        }
        // publish raw pivot rows + inverse pivots
        const int prw = gi - 4 * chunk;              // 0..3
        #pragma unroll
        for (int c = 0; c < 5; ++c) pivR[nb][prw][cb + c] = xr[c];
        if (gc == 0) pivI[nb][prw] = myipv;
    };

    // eliminate the 4 published pivots of `chunk` (buf bf) from my row.
    // Panel is mutually orthogonalized -> the 4 L factors are independent.
    auto eliminate = [&](int chunk, int bf) {
        #pragma unroll
        for (int p = 0; p < 4; ++p) {
            const int col = 4 * chunk + p;
            float2 cand = make_float2(0.f, 0.f);
            #pragma unroll
            for (int c = 0; c < 5; ++c)
                if (cb + c == col) cand = xr[c];
            float2 Lv;
            Lv.x = __shfl(cand.x, lanebase + col / 5);
            Lv.y = __shfl(cand.y, lanebase + col / 5);
            float2 ipv = pivI[bf][p];
            float2 L = cmul(Lv, ipv);
            #pragma unroll
            for (int c = 0; c < 5; ++c) {
                float2 pr = pivR[bf][p][cb + c];
                xr[c].x -= L.x * pr.x - L.y * pr.y;
                xr[c].y -= L.x * pr.y + L.y * pr.x;
            }
        }
    };

    int cur = 0;
    if (wv == 0) cascade(0, 0);
    __syncthreads();

    #pragma unroll 1
    for (int c = 0; c < 16; ++c) {
        if (wv != c) {
            eliminate(c, cur);
            if (wv == c + 1) cascade(c + 1, cur ^ 1);
        }
        __syncthreads();
        cur ^= 1;
    }

    // ---- extract solution (cols 64..79), normalize, write ----
    float ss = 0.f;
    if (gc >= 12) {
        #pragma unroll
        for (int c = 0; c < 5; ++c) {
            int col = cb + c;
            if (col >= 64) {
                float2 xv = cmul(xr[c], myipv);
                ss += xv.x * xv.x + xv.y * xv.y;
                xout[gi][col - 64] = xv;
            }
        }
    }
    #pragma unroll
    for (int off = 32; off; off >>= 1) ss += __shfl_xor(ss, off);
    if ((tid & 63) == 0) fred[wv] = ss;
    __syncthreads();
    float total = 0.f;
    #pragma unroll
    for (int w = 0; w < 16; ++w) total += fred[w];
    float invn = rsqrtf(total);
    {
        float2 v = xout[tid >> 4][tid & 15];
        out[(size_t)b * 1024 + tid] = make_float2(v.x * invn, v.y * invn);
    }
}

extern "C" void kernel_launch(void* const* d_in, const int* in_sizes, int n_in,
                              void* d_out, int out_size, void* d_ws, size_t ws_size,
                              hipStream_t stream) {
    const float* channel    = (const float*)d_in[0];
    const float* prediction = (const float*)d_in[1];
    int batch = in_sizes[0] / 65536;   // 256
    // workspace: [batch*2][64][80] float2 Aug partials, then [batch*2] float2 tr
    float2* wsAug = (float2*)d_ws;
    float2* wsTr  = wsAug + (size_t)batch * 2 * 5120;
    uw2v_build<<<dim3(batch * 2), dim3(512), 0, stream>>>(channel, prediction,
                                                          wsAug, wsTr);
    uw2v_gj<<<dim3(batch), dim3(1024), 0, stream>>>(wsAug, wsTr, (float2*)d_out);
}

// Round 7
// 166.152 us; speedup vs baseline: 1.5042x; 1.0839x over previous
//
#include <hip/hip_runtime.h>
#include <math.h>

// NT=64, NR=4, DK=2, KU=8, BR=16, BATCH=256
// channel:    [B][64][4][16][16] f32 (last dim: 8 re, 8 im)
// prediction: [B][2560] = U[4][2][16][16] ++ W[2][2][16][8]
// out:        [B][64][2][8][2] f32
//
// R15 = R8 monolith (95us dispatch, proven no-spill 120-VGPR codegen at
// 512 threads) + panel Gauss-Jordan from R14 (accuracy-verified there),
// scaled to 8 pivots/chunk:
//  - wave w owns rows 8w..8w+7 (8 thr/row); a chunk's 8-pivot cascade is
//    wave-local (shfl only). Owner publishes 8 raw pivot rows + ipv[8];
//    other waves eliminate 8 columns per barrier interval. 9 barriers
//    instead of 64 -> removes the dominant GJ stall (LDS round-trip +
//    barrier per pivot).
// Split experiments (R13/R14) abandoned: extra launch + 21MB workspace
// round-trip cost more than co-residency (never materialized) returned.

#define SAUG 84   // float2 stride of Aug rows
#define STP  65   // float4 stride of paired TtP/HtP rows

namespace {
union alignas(16) ShU {
    struct { float4 TtP[2][2][8][STP]; float4 HtP[2][2][8][STP]; } p1; // 66560 B
    float2 Aug[64][SAUG];                                              // 43008 B
};
union alignas(16) ShV {
    struct { float2 U[4 * 258]; float W[512]; } in;                    // 10304 B
    float2 xout[64][17];                                               // 8704 B
};
}

__device__ __forceinline__ float2 cmul(float2 x, float2 y) {
    return make_float2(x.x * y.x - x.y * y.y, x.x * y.y + x.y * y.x);
}

__global__ __launch_bounds__(512, 1)
void uw2v_kernel(const float* __restrict__ channel,
                 const float* __restrict__ prediction,
                 float2* __restrict__ out)
{
    __shared__ ShU sh;
    __shared__ ShV sv;
    __shared__ alignas(16) float2 pivR[2][8][80];  // chunk pivot rows (dbuf)
    __shared__ float2 pivI[2][8];                  // chunk inverse pivots
    __shared__ float2 redbuf[8];
    __shared__ float  fred[8];

    const int b   = blockIdx.x;
    const int tid = threadIdx.x;
    const int wv  = tid >> 6;
    const float* pred = prediction + (size_t)b * 2560;
    const float* chan = channel + (size_t)b * 65536;

    // ---- load U (re/im merged, padded per-r stride) and W ----
    #pragma unroll
    for (int i = 0; i < 2; ++i) {
        int m = tid + i * 512;                       // [r][d][f][k]
        int r = m >> 8, d = (m >> 7) & 1, f = (m >> 3) & 15, k = m & 7;
        const float* src = pred + (((r * 2 + d) * 16 + f) << 4);
        sv.in.U[r * 258 + ((d * 16 + f) << 3) + k] = make_float2(src[k], src[k + 8]);
    }
    sv.in.W[tid] = pred[2048 + tid];
    __syncthreads();

    const int half = tid >> 8;
    const int lt   = tid & 255;
    const int t4 = lt >> 2, r4 = lt & 3;
    const int a  = lt >> 4, bb = lt & 15;
    const int bit0 = r4 & 1, bit1 = (r4 >> 1) & 1;
    const int kkb  = 4 * bit0 + 2 * bit1;            // owned k-slice base (even)
    const int mpb  = kkb >> 1;                       // owned m-pair row (0..3)
    const int fbase = half << 3;
    const int tr_r = lt >> 5, tr_d = (lt >> 4) & 1, tr_e = (lt >> 3) & 1, tr_k = lt & 7;

    // split accumulators: accA = sum t_re*h, accB = sum t_im*h (h = (re,im))
    float2 accA[4][4], accB[4][4];
    #pragma unroll
    for (int i = 0; i < 4; ++i)
        #pragma unroll
        for (int j = 0; j < 4; ++j) {
            accA[i][j] = make_float2(0.f, 0.f);
            accB[i][j] = make_float2(0.f, 0.f);
        }
    float2 huw[4] = {make_float2(0,0), make_float2(0,0), make_float2(0,0), make_float2(0,0)};
    float2 tracc  = make_float2(0.f, 0.f);

    const float* hbase = chan + ((t4 * 4 + r4) << 8) + (fbase << 4);

    #pragma unroll 1
    for (int fi = 0; fi < 8; ++fi) {
        const int f = fbase + fi;
        const float4 ca = *(const float4*)(hbase + (fi << 4) + 0);
        const float4 cb = *(const float4*)(hbase + (fi << 4) + 4);
        const float4 ci = *(const float4*)(hbase + (fi << 4) + 8);
        const float4 cd = *(const float4*)(hbase + (fi << 4) + 12);

        const float4* U0p = (const float4*)&sv.in.U[r4 * 258 + (f << 3)];        // d=0
        const float4* U1p = (const float4*)&sv.in.U[r4 * 258 + ((16 + f) << 3)]; // d=1
        const float4 u0q0 = U0p[0], u0q1 = U0p[1], u0q2 = U0p[2], u0q3 = U0p[3];
        const float4 u1q0 = U1p[0], u1q1 = U1p[1], u1q2 = U1p[2], u1q3 = U1p[3];

        // partials: val0[k] = conj(H)*U (d=0, m=k), val1[k] (d=1, m=8+k)
        float2 val0[8], val1[8];
        #define MK2(K, HR, HI, U0R, U0I, U1R, U1I) \
            val0[K] = make_float2((HR)*(U0R) + (HI)*(U0I), (HR)*(U0I) - (HI)*(U0R)); \
            val1[K] = make_float2((HR)*(U1R) + (HI)*(U1I), (HR)*(U1I) - (HI)*(U1R));
        MK2(0, ca.x, ci.x, u0q0.x, u0q0.y, u1q0.x, u1q0.y)
        MK2(1, ca.y, ci.y, u0q0.z, u0q0.w, u1q0.z, u1q0.w)
        MK2(2, ca.z, ci.z, u0q1.x, u0q1.y, u1q1.x, u1q1.y)
        MK2(3, ca.w, ci.w, u0q1.z, u0q1.w, u1q1.z, u1q1.w)
        MK2(4, cb.x, cd.x, u0q2.x, u0q2.y, u1q2.x, u1q2.y)
        MK2(5, cb.y, cd.y, u0q2.z, u0q2.w, u1q2.z, u1q2.w)
        MK2(6, cb.z, cd.z, u0q3.x, u0q3.y, u1q3.x, u1q3.y)
        MK2(7, cb.w, cd.w, u0q3.z, u0q3.w, u1q3.z, u1q3.w)
        #undef MK2

        // stage 1 (xor 1): keep k in {4*bit0 .. 4*bit0+3}
        float2 s1d0[4], s1d1[4];
        #pragma unroll
        for (int q = 0; q < 4; ++q) {
            float2 k0 = bit0 ? val0[4 + q] : val0[q];
            float2 n0 = bit0 ? val0[q]     : val0[4 + q];
            float2 k1 = bit0 ? val1[4 + q] : val1[q];
            float2 n1 = bit0 ? val1[q]     : val1[4 + q];
            n0.x = __shfl_xor(n0.x, 1); n0.y = __shfl_xor(n0.y, 1);
            n1.x = __shfl_xor(n1.x, 1); n1.y = __shfl_xor(n1.y, 1);
            s1d0[q] = make_float2(k0.x + n0.x, k0.y + n0.y);
            s1d1[q] = make_float2(k1.x + n1.x, k1.y + n1.y);
        }
        // stage 2 (xor 2): keep q in {2*bit1, 2*bit1+1} -> hh[kkb+jj]
        float2 h0[2], h1[2];
        #pragma unroll
        for (int jj = 0; jj < 2; ++jj) {
            float2 k0 = bit1 ? s1d0[2 + jj] : s1d0[jj];
            float2 n0 = bit1 ? s1d0[jj]     : s1d0[2 + jj];
            float2 k1 = bit1 ? s1d1[2 + jj] : s1d1[jj];
            float2 n1 = bit1 ? s1d1[jj]     : s1d1[2 + jj];
            n0.x = __shfl_xor(n0.x, 2); n0.y = __shfl_xor(n0.y, 2);
            n1.x = __shfl_xor(n1.x, 2); n1.y = __shfl_xor(n1.y, 2);
            h0[jj] = make_float2(k0.x + n0.x, k0.y + n0.y);
            h1[jj] = make_float2(k1.x + n1.x, k1.y + n1.y);
        }

        // tr_UWU partial (128 lanes per half; wave-uniform branch)
        if (lt < 128) {
            float w   = sv.in.W[((tr_d * 2 + tr_e) * 16 + f) * 8 + tr_k];
            float2 u1 = sv.in.U[tr_r * 258 + ((tr_d * 16 + f) << 3) + tr_k];
            float2 u2 = sv.in.U[tr_r * 258 + ((tr_e * 16 + f) << 3) + tr_k];
            tracc.x += w * (u1.x * u2.x + u1.y * u2.y);
            tracc.y += w * (u1.y * u2.x - u1.x * u2.y);
        }

        // T pairs + H pairs (b128 writes, m-pair rows)
        const int p = fi & 1;
        #pragma unroll
        for (int e = 0; e < 2; ++e) {
            float w0a = sv.in.W[(e * 16 + f) * 8 + kkb];
            float w0b = sv.in.W[(e * 16 + f) * 8 + kkb + 1];
            float w1a = sv.in.W[((2 + e) * 16 + f) * 8 + kkb];
            float w1b = sv.in.W[((2 + e) * 16 + f) * 8 + kkb + 1];
            float2 tva = make_float2(h0[0].x * w0a + h1[0].x * w1a,
                                     h0[0].y * w0a + h1[0].y * w1a);
            float2 tvb = make_float2(h0[1].x * w0b + h1[1].x * w1b,
                                     h0[1].y * w0b + h1[1].y * w1b);
            sh.p1.TtP[p][half][e * 4 + mpb][t4] = make_float4(tva.x, tva.y, tvb.x, tvb.y);
            huw[e * 2 + 0].x += tva.x; huw[e * 2 + 0].y += tva.y;
            huw[e * 2 + 1].x += tvb.x; huw[e * 2 + 1].y += tvb.y;
        }
        sh.p1.HtP[p][half][mpb][t4]     = make_float4(h0[0].x, h0[0].y, h0[1].x, h0[1].y);
        sh.p1.HtP[p][half][4 + mpb][t4] = make_float4(h1[0].x, h1[0].y, h1[1].x, h1[1].y);
        __syncthreads();

        // quad: accA/accB [i][j] over m-pairs (b128 reads, broadcast-friendly)
        #pragma unroll
        for (int mp = 0; mp < 8; ++mp) {
            float4 tq[4], hq[4];
            #pragma unroll
            for (int i = 0; i < 4; ++i) tq[i] = sh.p1.TtP[p][half][mp][a + 16 * i];
            #pragma unroll
            for (int j = 0; j < 4; ++j) hq[j] = sh.p1.HtP[p][half][mp][bb + 16 * j];
            #pragma unroll
            for (int i = 0; i < 4; ++i)
                #pragma unroll
                for (int j = 0; j < 4; ++j) {
                    float2 va = accA[i][j], vb = accB[i][j];
                    va.x = fmaf(tq[i].x, hq[j].x, va.x);
                    va.y = fmaf(tq[i].x, hq[j].y, va.y);
                    vb.x = fmaf(tq[i].y, hq[j].x, vb.x);
                    vb.y = fmaf(tq[i].y, hq[j].y, vb.y);
                    va.x = fmaf(tq[i].z, hq[j].z, va.x);
                    va.y = fmaf(tq[i].z, hq[j].w, va.y);
                    vb.x = fmaf(tq[i].w, hq[j].z, vb.x);
                    vb.y = fmaf(tq[i].w, hq[j].w, vb.y);
                    accA[i][j] = va; accB[i][j] = vb;
                }
        }
    }

    // ---- tr_UWU block reduction ----
    #pragma unroll
    for (int off = 32; off; off >>= 1) {
        tracc.x += __shfl_xor(tracc.x, off);
        tracc.y += __shfl_xor(tracc.y, off);
    }
    if ((tid & 63) == 0) redbuf[wv] = tracc;
    __syncthreads();
    float2 trv = make_float2(0.f, 0.f);
    #pragma unroll
    for (int w = 0; w < 8; ++w) { trv.x += redbuf[w].x; trv.y += redbuf[w].y; }
    trv.x *= 0.1f; trv.y *= 0.1f;

    // ---- merge halves into Aug = [quad + trv*I | HUW] ----
    // qacc = (accA.x + accB.y, accB.x - accA.y)
    if (half == 0) {
        #pragma unroll
        for (int i = 0; i < 4; ++i)
            #pragma unroll
            for (int j = 0; j < 4; ++j) {
                float2 v = make_float2(accA[i][j].x + accB[i][j].y,
                                       accB[i][j].x - accA[i][j].y);
                int row = a + 16 * i, col = bb + 16 * j;
                if (row == col) { v.x += trv.x; v.y += trv.y; }
                sh.Aug[row][col] = v;
            }
        #pragma unroll
        for (int e = 0; e < 2; ++e)
            #pragma unroll
            for (int jj = 0; jj < 2; ++jj)
                sh.Aug[t4][64 + e * 8 + kkb + jj] = huw[e * 2 + jj];
    }
    __syncthreads();
    if (half == 1) {
        #pragma unroll
        for (int i = 0; i < 4; ++i)
            #pragma unroll
            for (int j = 0; j < 4; ++j) {
                int row = a + 16 * i, col = bb + 16 * j;
                float2 v = sh.Aug[row][col];
                v.x += accA[i][j].x + accB[i][j].y;
                v.y += accB[i][j].x - accA[i][j].y;
                sh.Aug[row][col] = v;
            }
        #pragma unroll
        for (int e = 0; e < 2; ++e)
            #pragma unroll
            for (int jj = 0; jj < 2; ++jj) {
                int col = 64 + e * 8 + kkb + jj;
                float2 v = sh.Aug[t4][col];
                v.x += huw[e * 2 + jj].x; v.y += huw[e * 2 + jj].y;
                sh.Aug[t4][col] = v;
            }
    }
    __syncthreads();

    // ---- panel Gauss-Jordan: 8 chunks of 8 pivots, wave-local cascades ----
    const int gi = tid >> 3, gc = tid & 7;           // row 0..63, col-slice 0..7
    const int cb = 10 * gc;                          // 10 cols per thread
    const int lanebase = (tid & 63) & 56;            // my row's base lane

    float2 xr[10];
    {
        const float4* rp = (const float4*)&sh.Aug[gi][cb];
        float4 q0 = rp[0], q1 = rp[1], q2 = rp[2], q3 = rp[3], q4 = rp[4];
        xr[0] = make_float2(q0.x, q0.y); xr[1] = make_float2(q0.z, q0.w);
        xr[2] = make_float2(q1.x, q1.y); xr[3] = make_float2(q1.z, q1.w);
        xr[4] = make_float2(q2.x, q2.y); xr[5] = make_float2(q2.z, q2.w);
        xr[6] = make_float2(q3.x, q3.y); xr[7] = make_float2(q3.z, q3.w);
        xr[8] = make_float2(q4.x, q4.y); xr[9] = make_float2(q4.z, q4.w);
    }

    float2 myipv = make_float2(0.f, 0.f);

    // wave-local cascade: in-panel GJ on my wave's 8 rows, publish to buf nb
    auto cascade = [&](int chunk, int nb) {
        #pragma unroll
        for (int p = 0; p < 8; ++p) {
            const int col = 8 * chunk + p;
            const int cs  = col / 10;                // owning col-slice
            float2 cand = make_float2(0.f, 0.f);
            #pragma unroll
            for (int c = 0; c < 10; ++c)
                if (cb + c == col) cand = xr[c];
            float2 z, Lv;
            z.x  = __shfl(cand.x, p * 8 + cs);
            z.y  = __shfl(cand.y, p * 8 + cs);
            Lv.x = __shfl(cand.x, lanebase + cs);
            Lv.y = __shfl(cand.y, lanebase + cs);
            float  zi  = 1.0f / (z.x * z.x + z.y * z.y);
            float2 ipv = make_float2(z.x * zi, -z.y * zi);
            const bool isPiv = (gi == col);
            if (isPiv) myipv = ipv;
            float2 pr[10];
            #pragma unroll
            for (int c = 0; c < 10; ++c) {
                pr[c].x = __shfl(xr[c].x, p * 8 + gc);
                pr[c].y = __shfl(xr[c].y, p * 8 + gc);
            }
            if (!isPiv) {
                float2 L = cmul(Lv, ipv);
                #pragma unroll
                for (int c = 0; c < 10; ++c) {
                    xr[c].x -= L.x * pr[c].x - L.y * pr[c].y;
                    xr[c].y -= L.x * pr[c].y + L.y * pr[c].x;
                }
            }
        }
        // publish raw pivot rows + inverse pivots
        const int prw = gi & 7;
        float4* wp = (float4*)&pivR[nb][prw][cb];
        wp[0] = make_float4(xr[0].x, xr[0].y, xr[1].x, xr[1].y);
        wp[1] = make_float4(xr[2].x, xr[2].y, xr[3].x, xr[3].y);
        wp[2] = make_float4(xr[4].x, xr[4].y, xr[5].x, xr[5].y);
        wp[3] = make_float4(xr[6].x, xr[6].y, xr[7].x, xr[7].y);
        wp[4] = make_float4(xr[8].x, xr[8].y, xr[9].x, xr[9].y);
        if (gc == 0) pivI[nb][prw] = myipv;
    };

    // eliminate the 8 published pivots of `chunk` (buf bf) from my row.
    auto eliminate = [&](int chunk, int bf) {
        #pragma unroll
        for (int p = 0; p < 8; ++p) {
            const int col = 8 * chunk + p;
            float2 cand = make_float2(0.f, 0.f);
            #pragma unroll
            for (int c = 0; c < 10; ++c)
                if (cb + c == col) cand = xr[c];
            float2 Lv;
            Lv.x = __shfl(cand.x, lanebase + col / 10);
            Lv.y = __shfl(cand.y, lanebase + col / 10);
            float2 ipv = pivI[bf][p];
            float2 L = cmul(Lv, ipv);
            const float4* pp = (const float4*)&pivR[bf][p][cb];
            float4 p0 = pp[0], p1 = pp[1], p2 = pp[2], p3 = pp[3], p4 = pp[4];
            float2 pr[10];
            pr[0] = make_float2(p0.x, p0.y); pr[1] = make_float2(p0.z, p0.w);
            pr[2] = make_float2(p1.x, p1.y); pr[3] = make_float2(p1.z, p1.w);
            pr[4] = make_float2(p2.x, p2.y); pr[5] = make_float2(p2.z, p2.w);
            pr[6] = make_float2(p3.x, p3.y); pr[7] = make_float2(p3.z, p3.w);
            pr[8] = make_float2(p4.x, p4.y); pr[9] = make_float2(p4.z, p4.w);
            #pragma unroll
            for (int c = 0; c < 10; ++c) {
                xr[c].x -= L.x * pr[c].x - L.y * pr[c].y;
                xr[c].y -= L.x * pr[c].y + L.y * pr[c].x;
            }
        }
    };

    int cur = 0;
    if (wv == 0) cascade(0, 0);
    __syncthreads();

    #pragma unroll 1
    for (int c = 0; c < 8; ++c) {
        if (wv != c) {
            eliminate(c, cur);
            if (wv == c + 1) cascade(c + 1, cur ^ 1);
        }
        __syncthreads();
        cur ^= 1;
    }

    // ---- extract solution (cols 64..79), normalize, write ----
    float ss = 0.f;
    if (gc == 6) {
        #pragma unroll
        for (int c = 4; c < 10; ++c) {
            float2 xv = cmul(xr[c], myipv);
            ss += xv.x * xv.x + xv.y * xv.y;
            sv.xout[gi][c - 4] = xv;
        }
    } else if (gc == 7) {
        #pragma unroll
        for (int c = 0; c < 10; ++c) {
            float2 xv = cmul(xr[c], myipv);
            ss += xv.x * xv.x + xv.y * xv.y;
            sv.xout[gi][6 + c] = xv;
        }
    }
    #pragma unroll
    for (int off = 32; off; off >>= 1) ss += __shfl_xor(ss, off);
    if ((tid & 63) == 0) fred[wv] = ss;
    __syncthreads();
    float total = 0.f;
    #pragma unroll
    for (int w = 0; w < 8; ++w) total += fred[w];
    float invn = rsqrtf(total);
    #pragma unroll
    for (int q = 0; q < 2; ++q) {
        int m = tid + q * 512;
        float2 v = sv.xout[m >> 4][m & 15];
        out[(size_t)b * 1024 + m] = make_float2(v.x * invn, v.y * invn);
    }
}

extern "C" void kernel_launch(void* const* d_in, const int* in_sizes, int n_in,
                              void* d_out, int out_size, void* d_ws, size_t ws_size,
                              hipStream_t stream) {
    const float* channel    = (const float*)d_in[0];
    const float* prediction = (const float*)d_in[1];
    int batch = in_sizes[0] / 65536;   // 256
    uw2v_kernel<<<dim3(batch), dim3(512), 0, stream>>>(channel, prediction,
                                                       (float2*)d_out);
}